// Round 4
// baseline (531.735 us; speedup 1.0000x reference)
//
#include <hip/hip_runtime.h>
#include <hip/hip_bf16.h>

// Problem constants
#define B_     8
#define N_     1024
#define DIM_   512
#define H_     8
#define HD_    64
#define INNER_ 512
#define QKVC   2048   // 4*INNER
#define M_     8192   // B*N

typedef __attribute__((ext_vector_type(8))) short short8;
typedef __attribute__((ext_vector_type(4))) float f32x4;
#define MFMA_BF16 __builtin_amdgcn_mfma_f32_16x16x32_bf16

__device__ __forceinline__ unsigned short f2b(float x) {
    __hip_bfloat16 h = __float2bfloat16(x);
    unsigned short u; __builtin_memcpy(&u, &h, 2); return u;
}
// pack bf16 hi/lo split of x into one u32: (hi<<16)|lo
__device__ __forceinline__ unsigned int packsplit(float x) {
    unsigned int hb = f2b(x);
    float fh = __uint_as_float(hb << 16);
    unsigned int lb = f2b(x - fh);
    return (hb << 16) | lb;
}
__device__ __forceinline__ void split8(const float* v, short8& h, short8& l) {
#pragma unroll
    for (int i = 0; i < 8; i++) {
        unsigned int hb = f2b(v[i]);
        float fh = __uint_as_float(hb << 16);
        h[i] = (short)hb; l[i] = (short)f2b(v[i] - fh);
    }
}
// hi/lo split of two floats -> packed u32s (ushort order: a in low, b in high)
__device__ __forceinline__ void split2x2(float a, float b, unsigned int& h, unsigned int& l) {
    unsigned int ha = f2b(a), hb = f2b(b);
    float fa = __uint_as_float(ha << 16), fb = __uint_as_float(hb << 16);
    h = ha | (hb << 16);
    l = (unsigned int)f2b(a - fa) | ((unsigned int)f2b(b - fb) << 16);
}

// async global->LDS, 16B per lane, LDS dest = wave-uniform base + lane*16
__device__ __forceinline__ void gll16(const unsigned short* g, unsigned short* l) {
    __builtin_amdgcn_global_load_lds(
        (const __attribute__((address_space(1))) void*)g,
        (__attribute__((address_space(3))) void*)l, 16, 0, 0);
}

// ---------------------------------------------------------------------------
// Layout notes
//  K planar image: per token row, [hi-plane D ushorts][lo-plane D ushorts].
//    Consumer (mattn) folds the sK chunk swizzle lq = q ^ (row&15) into the
//    per-lane gll SOURCE offset; the global image itself is linear -> both
//    producers (gemm PACKK epilogue, convgate) write coalesced.
//  V image: per (b,h), 16 blocks of 64 tokens; each block is the EXACT sV
//    LDS image (4096 ushorts): idx = d*64 + (((j>>3) ^ ((d^(d>>2))&7))<<3)
//    + (j&7). Consumer stages with ONE linear gll16 per thread.
// ---------------------------------------------------------------------------

// ---------------------------------------------------------------------------
// Tiled-swizzled planar pack (pre-computed LDS image) for the GEMM.
// Tile (rt, kt) = 16KB = 8192 ushorts at base + (rt*16 + kt)*8192.
// ---------------------------------------------------------------------------
__global__ __launch_bounds__(256)
void pack_a_tiled(const float* __restrict__ in, unsigned short* __restrict__ out)
{
    size_t i = ((size_t)blockIdx.x * 256 + threadIdx.x) * 4;   // element idx, K=512 cols
    float4 v = *(const float4*)(in + i);
    const size_t R = i >> 9;          // row
    const int k  = (int)(i & 511);    // col (multiple of 4)
    const int kt = k >> 5, kk = k & 31;
    const int r  = (int)(R & 127);
    const size_t rt = R >> 7;
    unsigned short* tile = out + (((rt << 4) + kt) << 13) + r * 64;
    unsigned int h01, l01, h23, l23;
    split2x2(v.x, v.y, h01, l01);
    split2x2(v.z, v.w, h23, l23);
    uint2 hv; hv.x = h01; hv.y = h23;
    uint2 lv; lv.x = l01; lv.y = l23;
    const int s7 = r & 7;
    *(uint2*)&tile[(((kk >> 3)     ^ s7) << 3) + (kk & 7)] = hv;
    *(uint2*)&tile[((((kk >> 3)+4) ^ s7) << 3) + (kk & 7)] = lv;
}

// W[k][n] (f32, K=512 rows, N cols) -> B^T tiled-swizzled image (rows = n)
__global__ __launch_bounds__(256)
void pack_w_tiled(const float* __restrict__ W, unsigned short* __restrict__ out, int N)
{
    const int n  = blockIdx.x * 256 + threadIdx.x;
    const int k0 = blockIdx.y * 4;
    float f0 = W[(size_t)(k0 + 0) * N + n];
    float f1 = W[(size_t)(k0 + 1) * N + n];
    float f2 = W[(size_t)(k0 + 2) * N + n];
    float f3 = W[(size_t)(k0 + 3) * N + n];
    const int r  = n & 127;
    const size_t rt = n >> 7;
    const int kt = k0 >> 5, kk = k0 & 31;
    unsigned short* tile = out + (((rt << 4) + kt) << 13) + r * 64;
    unsigned int h01, l01, h23, l23;
    split2x2(f0, f1, h01, l01);
    split2x2(f2, f3, h23, l23);
    uint2 hv; hv.x = h01; hv.y = h23;
    uint2 lv; lv.x = l01; lv.y = l23;
    const int s7 = r & 7;
    *(uint2*)&tile[(((kk >> 3)     ^ s7) << 3) + (kk & 7)] = hv;
    *(uint2*)&tile[((((kk >> 3)+4) ^ s7) << 3) + (kk & 7)] = lv;
}

// Old format pack (kept for out-proj GEMM): W[k][n] -> Wt[n][k] packed u32
__global__ __launch_bounds__(256)
void pack_wt(const float* __restrict__ W, unsigned int* __restrict__ Wt, int N)
{
    const int n = blockIdx.x * 256 + threadIdx.x;
    const int k0 = blockIdx.y * 4;
    uint4 p;
    p.x = packsplit(W[(size_t)(k0 + 0) * N + n]);
    p.y = packsplit(W[(size_t)(k0 + 1) * N + n]);
    p.z = packsplit(W[(size_t)(k0 + 2) * N + n]);
    p.w = packsplit(W[(size_t)(k0 + 3) * N + n]);
    *(uint4*)&Wt[(size_t)n * 512 + k0] = p;
}

// ---------------------------------------------------------------------------
// MFMA split-GEMM, global_load_lds staging from pre-swizzled tiled inputs.
// PACKK: k-slice cols [512,1024) -> planar K-image via LDS transpose so the
// global stores are coalesced uint4 runs (fixes the 2-byte-scatter epilogue).
// ---------------------------------------------------------------------------
template<bool BIAS, bool PACKK>
__global__ __launch_bounds__(256)
void gemm_gll(const unsigned short* __restrict__ At, const unsigned short* __restrict__ Bt,
              const float* __restrict__ bias, float* __restrict__ Cp,
              int M, int N)
{
    __shared__ __align__(16) unsigned short sA[128 * 64];
    __shared__ __align__(16) unsigned short sB[128 * 64];

    const int t    = threadIdx.x;
    const int lane = t & 63;
    const int w    = t >> 6;
    const int n16  = lane & 15, quad = lane >> 4;
    const int wm   = w >> 1, wn = w & 1;
    const int m0 = blockIdx.y * 128, n0 = blockIdx.x * 128;

    f32x4 acc[4][4];
#pragma unroll
    for (int mt = 0; mt < 4; mt++)
#pragma unroll
        for (int nt = 0; nt < 4; nt++) acc[mt][nt] = (f32x4){0.f, 0.f, 0.f, 0.f};

    const unsigned short* Ag = At + ((size_t)blockIdx.y << 4) * 8192 + (w * 64 + lane) * 8;
    const unsigned short* Bg = Bt + ((size_t)blockIdx.x << 4) * 8192 + (w * 64 + lane) * 8;
    unsigned short* sAw = &sA[w * 512];
    unsigned short* sBw = &sB[w * 512];

    for (int kt = 0; kt < 16; kt++) {
        __syncthreads();
        const size_t ko = (size_t)kt * 8192;
#pragma unroll
        for (int i = 0; i < 4; i++) {
            gll16(Ag + ko + i * 2048, sAw + i * 2048);
            gll16(Bg + ko + i * 2048, sBw + i * 2048);
        }
        __syncthreads();

        short8 Ah[4], Al[4];
#pragma unroll
        for (int mt = 0; mt < 4; mt++) {
            const int row = 64 * wm + 16 * mt + n16;
            const int base = row * 64;
            const int s7 = row & 7;
            Ah[mt] = *(const short8*)&sA[base + (((quad    ) ^ s7) << 3)];
            Al[mt] = *(const short8*)&sA[base + (((quad + 4) ^ s7) << 3)];
        }
#pragma unroll
        for (int nt = 0; nt < 4; nt++) {
            const int row = 64 * wn + 16 * nt + n16;
            const int base = row * 64;
            const int s7 = row & 7;
            short8 Bh = *(const short8*)&sB[base + (((quad    ) ^ s7) << 3)];
            short8 Bl = *(const short8*)&sB[base + (((quad + 4) ^ s7) << 3)];
#pragma unroll
            for (int mt = 0; mt < 4; mt++) {
                acc[mt][nt] = MFMA_BF16(Ah[mt], Bh, acc[mt][nt], 0, 0, 0);
                acc[mt][nt] = MFMA_BF16(Al[mt], Bh, acc[mt][nt], 0, 0, 0);
                acc[mt][nt] = MFMA_BF16(Ah[mt], Bl, acc[mt][nt], 0, 0, 0);
            }
        }
    }

    const bool packout = PACKK && ((n0 >> 9) == 1);   // qkv k-slice cols
    if (packout) {
        // LDS-transpose epilogue: coalesced planar K-image stores.
        const int col0 = n0 - 512;
#pragma unroll 1
        for (int pass = 0; pass < 2; pass++) {
            __syncthreads();
            if (wm == pass) {
#pragma unroll
                for (int mt = 0; mt < 4; mt++)
#pragma unroll
                    for (int r = 0; r < 4; r++)
#pragma unroll
                        for (int nt = 0; nt < 4; nt++) {
                            const int rr = 16 * mt + 4 * quad + r;   // 0..63
                            const int cl = 64 * wn + 16 * nt + n16;  // 0..127
                            const float v = acc[mt][nt][r];
                            unsigned int hb = f2b(v);
                            float fh = __uint_as_float(hb << 16);
                            const int off = rr * 128 + ((((cl >> 3) ^ (rr & 7)) << 3)) + (cl & 7);
                            sA[off] = (unsigned short)hb;
                            sB[off] = f2b(v - fh);
                        }
            }
            __syncthreads();
            const int rr = t >> 2, seg = t & 3;
            const int row = m0 + pass * 64 + rr;
            unsigned short* kim = (unsigned short*)Cp + (size_t)row * (2 * N)
                                + 1024 + col0 + seg * 32;
#pragma unroll
            for (int i = 0; i < 4; i++) {
                const int po = rr * 128 + ((((seg * 4 + i) ^ (rr & 7))) << 3);
                *(uint4*)(kim + 8 * i)       = *(const uint4*)&sA[po];
                *(uint4*)(kim + 512 + 8 * i) = *(const uint4*)&sB[po];
            }
        }
    } else {
        float bv[4];
#pragma unroll
        for (int nt = 0; nt < 4; nt++)
            bv[nt] = BIAS ? bias[n0 + 64 * wn + 16 * nt + n16] : 0.f;
#pragma unroll
        for (int mt = 0; mt < 4; mt++) {
            const int rbase = m0 + 64 * wm + 16 * mt + 4 * quad;
#pragma unroll
            for (int r = 0; r < 4; r++) {
#pragma unroll
                for (int nt = 0; nt < 4; nt++) {
                    const int col = n0 + 64 * wn + 16 * nt + n16;
                    Cp[(size_t)(rbase + r) * N + col] = acc[mt][nt][r] + bv[nt];
                }
            }
        }
    }
}

// ---------------------------------------------------------------------------
// OLD register-staged split-GEMM (kept for out-proj: A comes packed u32 from
// the attention epilogue).
// ---------------------------------------------------------------------------
template<bool BIAS>
__global__ __launch_bounds__(256)
void gemm_mfma(const unsigned int* __restrict__ Ap, const unsigned int* __restrict__ Btp,
               const float* __restrict__ bias, float* __restrict__ Cp,
               int M, int N)
{
    const int K = 512;
    __shared__ __align__(16) unsigned short sA[128 * 64];
    __shared__ __align__(16) unsigned short sB[128 * 64];

    const int t    = threadIdx.x;
    const int lane = t & 63;
    const int w    = t >> 6;
    const int n16  = lane & 15, quad = lane >> 4;
    const int wm   = w >> 1, wn = w & 1;
    const int m0 = blockIdx.y * 128, n0 = blockIdx.x * 128;

    f32x4 acc[4][4];
#pragma unroll
    for (int mt = 0; mt < 4; mt++)
#pragma unroll
        for (int nt = 0; nt < 4; nt++) acc[mt][nt] = (f32x4){0.f, 0.f, 0.f, 0.f};

    const int srow = t >> 1;
    const int kb   = (t & 1) * 16;
    const unsigned int* ag = Ap  + (size_t)(m0 + srow) * K + kb;
    const unsigned int* bg = Btp + (size_t)(n0 + srow) * K + kb;
    const int s7s = srow & 7;
    unsigned short* swA = &sA[srow * 64];
    unsigned short* swB = &sB[srow * 64];

    for (int k0 = 0; k0 < K; k0 += 32) {
        __syncthreads();
#pragma unroll
        for (int i = 0; i < 4; i++) {
            const int kk = kb + i * 4;
            const int ch = kk >> 3;
            const int ho = kk & 4;
            const int c_hi = ((ch    ) ^ s7s) << 3;
            const int c_lo = ((ch + 4) ^ s7s) << 3;
            uint4 va = *(const uint4*)(ag + k0 + i * 4);
            uint4 vb = *(const uint4*)(bg + k0 + i * 4);
            uint2 ha, la, hb, lb;
            ha.x = (va.y & 0xFFFF0000u) | (va.x >> 16);
            ha.y = (va.w & 0xFFFF0000u) | (va.z >> 16);
            la.x = (va.y << 16) | (va.x & 0xFFFFu);
            la.y = (va.w << 16) | (va.z & 0xFFFFu);
            hb.x = (vb.y & 0xFFFF0000u) | (vb.x >> 16);
            hb.y = (vb.w & 0xFFFF0000u) | (vb.z >> 16);
            lb.x = (vb.y << 16) | (vb.x & 0xFFFFu);
            lb.y = (vb.w << 16) | (vb.z & 0xFFFFu);
            *(uint2*)&swA[c_hi + ho] = ha;
            *(uint2*)&swA[c_lo + ho] = la;
            *(uint2*)&swB[c_hi + ho] = hb;
            *(uint2*)&swB[c_lo + ho] = lb;
        }
        __syncthreads();

        short8 Ah[4], Al[4];
#pragma unroll
        for (int mt = 0; mt < 4; mt++) {
            const int row = 64 * wm + 16 * mt + n16;
            const int base = row * 64;
            const int s7 = row & 7;
            Ah[mt] = *(const short8*)&sA[base + (((quad    ) ^ s7) << 3)];
            Al[mt] = *(const short8*)&sA[base + (((quad + 4) ^ s7) << 3)];
        }
#pragma unroll
        for (int nt = 0; nt < 4; nt++) {
            const int row = 64 * wn + 16 * nt + n16;
            const int base = row * 64;
            const int s7 = row & 7;
            short8 Bh = *(const short8*)&sB[base + (((quad    ) ^ s7) << 3)];
            short8 Bl = *(const short8*)&sB[base + (((quad + 4) ^ s7) << 3)];
#pragma unroll
            for (int mt = 0; mt < 4; mt++) {
                acc[mt][nt] = MFMA_BF16(Ah[mt], Bh, acc[mt][nt], 0, 0, 0);
                acc[mt][nt] = MFMA_BF16(Al[mt], Bh, acc[mt][nt], 0, 0, 0);
                acc[mt][nt] = MFMA_BF16(Ah[mt], Bl, acc[mt][nt], 0, 0, 0);
            }
        }
    }

    float bv[4];
#pragma unroll
    for (int nt = 0; nt < 4; nt++)
        bv[nt] = BIAS ? bias[n0 + 64 * wn + 16 * nt + n16] : 0.f;
#pragma unroll
    for (int mt = 0; mt < 4; mt++) {
        const int rbase = m0 + 64 * wm + 16 * mt + 4 * quad;
#pragma unroll
        for (int r = 0; r < 4; r++) {
#pragma unroll
            for (int nt = 0; nt < 4; nt++) {
                const int col = n0 + 64 * wn + 16 * nt + n16;
                Cp[(size_t)(rbase + r) * N + col] = acc[mt][nt][r] + bv[nt];
            }
        }
    }
}

// ---------------------------------------------------------------------------
// Depthwise conv (k=5, pad=2) + sigmoid gate. Writes MSg (f32) + planar
// K-image [bh][n][hi 64 | lo 64] for attention A.
// ---------------------------------------------------------------------------
__global__ __launch_bounds__(128)
void convgate_kernel(const float* __restrict__ qkv1, const float* __restrict__ qkv2,
                     const float* __restrict__ convw,
                     const float* __restrict__ convb,
                     float* __restrict__ MSg, unsigned short* __restrict__ Kimg)
{
    __shared__ float ms[INNER_];
    const int blk = blockIdx.x;
    const int n = blk & (N_ - 1);
    const int b = blk >> 10;
    const int t = threadIdx.x;

    const float4* q1 = (const float4*)(qkv1 + (size_t)blk * QKVC + 3 * INNER_);
    const float4* q2 = (const float4*)(qkv2 + (size_t)blk * QKVC + 3 * INNER_);
    float4 v1 = q1[t], v2 = q2[t];
    float4 s;
    s.x = v1.x + v2.x; s.y = v1.y + v2.y; s.z = v1.z + v2.z; s.w = v1.w + v2.w;
    *(float4*)&ms[t * 4] = s;
    __syncthreads();

    float w[5];
#pragma unroll
    for (int k = 0; k < 5; k++) w[k] = convw[n * 5 + k];
    const float cb = convb[n];

    float out[4];
#pragma unroll
    for (int ff = 0; ff < 4; ff++) {
        int f = t * 4 + ff;
        float A = cb;
#pragma unroll
        for (int k = 0; k < 5; k++) {
            int idx = f + k - 2;
            if (idx >= 0 && idx < INNER_) A += ms[idx] * w[k];
        }
        float sg = 1.f / (1.f + __expf(-A));
        out[ff] = ms[f] * sg;
    }
    *(float4*)&MSg[(size_t)blk * INNER_ + t * 4] = make_float4(out[0], out[1], out[2], out[3]);

    // planar K-image write: head h = t>>4, dims d0..d0+3, token row n
    const int h  = t >> 4;
    const int d0 = (4 * t) & 63;
    unsigned short hs[4], ls[4];
#pragma unroll
    for (int e = 0; e < 4; e++) {
        unsigned int hb = f2b(out[e]);
        float fh = __uint_as_float(hb << 16);
        hs[e] = (unsigned short)hb;
        ls[e] = f2b(out[e] - fh);
    }
    unsigned short* kim = Kimg + ((size_t)(b * 8 + h) * 1024 + n) * 128 + d0;
    uint2 hv; hv.x = (unsigned int)hs[0] | ((unsigned int)hs[1] << 16);
              hv.y = (unsigned int)hs[2] | ((unsigned int)hs[3] << 16);
    uint2 lv; lv.x = (unsigned int)ls[0] | ((unsigned int)ls[1] << 16);
              lv.y = (unsigned int)ls[2] | ((unsigned int)ls[3] << 16);
    *(uint2*)kim        = hv;
    *(uint2*)(kim + 64) = lv;
}

// ---------------------------------------------------------------------------
// MFMA flash attention v6: 512 threads, Q-tile 128, 2-deep pipelined staging.
// K (and V if VIMG) double-buffered, staged via gll with COUNTED vmcnt —
// loads for tile t+1 stay in flight across compute(t) (T3/T4).
// Softmax in log2 domain (Q pre-scaled by 0.125*log2e) with defer-max.
// ---------------------------------------------------------------------------
template<int NV, bool RESID, bool PACKO, bool IMGO, bool VIMG, int NPROB>
__global__ __launch_bounds__(512, 2)
void mattn_kernel(const float* __restrict__ Q0, const float* __restrict__ Q1,
                  const unsigned short* __restrict__ K0, const unsigned short* __restrict__ K1,
                  const float* __restrict__ VA0, const float* __restrict__ VA1,
                  const float* __restrict__ VB0, const float* __restrict__ VB1,
                  float* __restrict__ OA0, float* __restrict__ OA1,
                  float* __restrict__ OB0, float* __restrict__ OB1,
                  long long q_sb, long long q_sh, int q_sr,
                  long long k_sb, long long k_sh, int k_rs, int k_po,
                  long long v_sb, long long v_sh, int v_sr,
                  long long o_sb, long long o_sh, int o_sr)
{
    __shared__ __align__(16) unsigned short sK[2 * 64 * 128];     // dbuf hi|lo planes
    __shared__ __align__(16) unsigned short sV0[(VIMG ? 2 : 1) * 64 * 64];
    __shared__ __align__(16) unsigned short sV1[(NV == 2) ? 64 * 64 : 8];
    __shared__ __align__(16) unsigned short sP[128 * 64];         // P bf16 / epi xpose

    const int t    = threadIdx.x;
    const int w    = t >> 6;        // wave 0..7
    const int lane = t & 63;
    const int n16  = lane & 15;
    const int quad = lane >> 4;

    // XCD-aware decode
    const int bid = blockIdx.x;
    const int c   = bid & 7;
    const int r1  = bid >> 3;
    const int qt  = r1 & 7;
    const int r2  = r1 >> 3;
    const int g   = r2 & 7;
    const int p   = (NPROB == 2) ? (r2 >> 3) : 0;
    const int bh  = 8 * g + c;
    const int b = bh >> 3, h = bh & 7;
    const int i0 = qt * 128;

    const float* Qb          = (NPROB == 2 && p) ? Q1 : Q0;
    const unsigned short* Kb = (NPROB == 2 && p) ? K1 : K0;
    const float* VAb         = (NPROB == 2 && p) ? VA1 : VA0;
    float* OAb               = (NPROB == 2 && p) ? OA1 : OA0;

    const float* Qg          = Qb + (size_t)b * q_sb + (size_t)h * q_sh;
    const unsigned short* Kg = Kb + (size_t)b * k_sb + (size_t)h * k_sh;

    const float* V0g = nullptr;
    const float* V1g = nullptr;
    const unsigned short* Vus = nullptr;
    if constexpr (VIMG) {
        Vus = (const unsigned short*)VAb + (size_t)b * v_sb + (size_t)h * v_sh;
    } else {
        V0g = VAb + (size_t)b * v_sb + (size_t)h * v_sh;
        if constexpr (NV == 2)
            V1g = VB0 + (size_t)b * v_sb + (size_t)h * v_sh;
    }

    float* O0g = nullptr; float* O1g = nullptr;
    unsigned short* img0 = nullptr; unsigned short* img1 = nullptr;
    if constexpr (IMGO) {
        img0 = (unsigned short*)OAb + (size_t)b * o_sb + (size_t)h * o_sh;
        if constexpr (NV == 2)
            img1 = (unsigned short*)OB0 + (size_t)b * o_sb + (size_t)h * o_sh;
    } else {
        O0g = OAb + (size_t)b * o_sb + (size_t)h * o_sh;
        if constexpr (NV == 2)
            O1g = OB0 + (size_t)b * o_sb + (size_t)h * o_sh;
    }

    // persistent Q fragments (hi/lo split), rows i0+16w+n16,
    // pre-scaled by 0.125 * log2(e) so exps are bare v_exp_f32.
    const float SC2 = 0.1803368801f;
    short8 Qh[2], Ql[2];
#pragma unroll
    for (int s = 0; s < 2; s++) {
        const float* qp = Qg + (size_t)(i0 + 16 * w + n16) * q_sr + 32 * s + 8 * quad;
        float qv[8];
        float4 q0 = *(const float4*)qp;
        float4 q1 = *(const float4*)(qp + 4);
        qv[0]=q0.x*SC2; qv[1]=q0.y*SC2; qv[2]=q0.z*SC2; qv[3]=q0.w*SC2;
        qv[4]=q1.x*SC2; qv[5]=q1.y*SC2; qv[6]=q1.z*SC2; qv[7]=q1.w*SC2;
        split8(qv, Qh[s], Ql[s]);
    }

    float m_ = -1e30f, l_ = 0.f;
    f32x4 O0a[4], O1a[(NV == 2) ? 4 : 1];
#pragma unroll
    for (int nt = 0; nt < 4; nt++) O0a[nt] = (f32x4){0.f,0.f,0.f,0.f};
    if constexpr (NV == 2) {
#pragma unroll
        for (int nt = 0; nt < 4; nt++) O1a[nt] = (f32x4){0.f,0.f,0.f,0.f};
    }

    const int prow = 16 * w + n16;          // 0..127
    const int vc = t & 15, vp = t >> 4;     // V f32 staging: d-chunk, j-pair

    // K staging: lane l of wave w fills sK rows jr=4w+(l>>4) (+32), chunk q=l&15.
    // Planar source: logical chunk lq = q ^ (jr&15) -> plane lq>>3, dchunk lq&7.
    const int jr_l = (w << 2) + (lane >> 4);
    const int lq   = (lane & 15) ^ (jr_l & 15);
    const unsigned short* kg_base = Kg + (size_t)jr_l * k_rs
                                  + (lq >> 3) * k_po + (lq & 7) * 8;
    unsigned short* sKw = &sK[w * 512];

    // ---- prologue: issue tile 0 (and tile 1 if full-gll path)
    if constexpr (VIMG) {
        gll16(kg_base, sKw);
        gll16(kg_base + (size_t)32 * k_rs, sKw + 4096);
        gll16(Vus + t * 8, &sV0[w * 512]);
        const unsigned short* kg1 = kg_base + (size_t)64 * k_rs;
        gll16(kg1, sKw + 8192);
        gll16(kg1 + (size_t)32 * k_rs, sKw + 8192 + 4096);
        gll16(Vus + 4096 + t * 8, &sV0[4096 + w * 512]);
    } else {
        gll16(kg_base, sKw);
        gll16(kg_base + (size_t)32 * k_rs, sKw + 4096);
    }
    __builtin_amdgcn_sched_barrier(0);

    int buf = 0;
#pragma unroll 1
    for (int j0 = 0; j0 < N_; j0 += 64) {
        if constexpr (!VIMG) {
            // V f32 loads FIRST (so the compiler's wait for them leaves the
            // younger K-glls in flight), then issue K(t+1), then cvt+write.
            const int j = 2 * vp;
            const float* a0 = V0g + (size_t)(j0 + j) * v_sr + 4 * vc;
            float4 va = *(const float4*)a0;
            float4 vb = *(const float4*)(a0 + v_sr);
            float4 wa, wb;
            if constexpr (NV == 2) {
                const float* a1 = V1g + (size_t)(j0 + j) * v_sr + 4 * vc;
                wa = *(const float4*)a1;
                wb = *(const float4*)(a1 + v_sr);
            }
            __builtin_amdgcn_sched_barrier(0);
            if (j0 < N_ - 64) {
                const unsigned short* kg = kg_base + (size_t)(j0 + 64) * k_rs;
                unsigned short* dK = &sK[(buf ^ 1) * 8192 + w * 512];
                gll16(kg, dK);
                gll16(kg + (size_t)32 * k_rs, dK + 4096);
            }
            __builtin_amdgcn_sched_barrier(0);
#pragma unroll
            for (int e = 0; e < 4; e++) {
                float fa = (e==0)?va.x:(e==1)?va.y:(e==2)?va.z:va.w;
                float fb = (e==0)?vb.x:(e==1)?vb.y:(e==2)?vb.z:vb.w;
                unsigned int u = (unsigned int)f2b(fa) | ((unsigned int)f2b(fb) << 16);
                const int d = 4 * vc + e;
                const int phys = (vp >> 2) ^ ((d ^ (d >> 2)) & 7);
                *(unsigned int*)&sV0[d * 64 + (phys << 3) + (j & 7)] = u;
            }
            if constexpr (NV == 2) {
#pragma unroll
                for (int e = 0; e < 4; e++) {
                    float fa = (e==0)?wa.x:(e==1)?wa.y:(e==2)?wa.z:wa.w;
                    float fb = (e==0)?wb.x:(e==1)?wb.y:(e==2)?wb.z:wb.w;
                    unsigned int u = (unsigned int)f2b(fa) | ((unsigned int)f2b(fb) << 16);
                    const int d = 4 * vc + e;
                    const int phys = (vp >> 2) ^ ((d ^ (d >> 2)) & 7);
                    *(unsigned int*)&sV1[d * 64 + (phys << 3) + (j & 7)] = u;
                }
            }
            if (j0 < N_ - 64) asm volatile("s_waitcnt vmcnt(2) lgkmcnt(0)" ::: "memory");
            else              asm volatile("s_waitcnt vmcnt(0) lgkmcnt(0)" ::: "memory");
        } else {
            if (j0 < N_ - 64) asm volatile("s_waitcnt vmcnt(3)" ::: "memory");
            else              asm volatile("s_waitcnt vmcnt(0)" ::: "memory");
        }
        __builtin_amdgcn_sched_barrier(0);
        __builtin_amdgcn_s_barrier();
        __builtin_amdgcn_sched_barrier(0);

        // ---- S^T = K.Q^T, split 3-MFMA, frags straight from planes
        const unsigned short* sKb = &sK[buf * 8192];
        const unsigned short* sVb0 = VIMG ? &sV0[buf * 4096] : &sV0[0];
        f32x4 accS[4];
#pragma unroll
        for (int mt = 0; mt < 4; mt++) accS[mt] = (f32x4){0.f,0.f,0.f,0.f};
#pragma unroll
        for (int s = 0; s < 2; s++) {
#pragma unroll
            for (int mt = 0; mt < 4; mt++) {
                const unsigned short* kb2 = &sKb[(16 * mt + n16) * 128];
                short8 kh = *(const short8*)&kb2[(((4*s + quad)    ) ^ n16) << 3];
                short8 kl = *(const short8*)&kb2[(((4*s + quad) + 8) ^ n16) << 3];
                accS[mt] = MFMA_BF16(kl, Qh[s], accS[mt], 0, 0, 0);
                accS[mt] = MFMA_BF16(kh, Ql[s], accS[mt], 0, 0, 0);
                accS[mt] = MFMA_BF16(kh, Qh[s], accS[mt], 0, 0, 0);
            }
        }

        // ---- online softmax (log2 domain), defer-max, wave-local P store
        float tmax = -1e30f;
#pragma unroll
        for (int mt = 0; mt < 4; mt++)
#pragma unroll
            for (int r = 0; r < 4; r++) tmax = fmaxf(tmax, accS[mt][r]);
        tmax = fmaxf(tmax, __shfl_xor(tmax, 16));
        tmax = fmaxf(tmax, __shfl_xor(tmax, 32));
        if (!__all(tmax <= m_ + 11.0f)) {
            const float mnew = fmaxf(m_, tmax);
            const float alpha = __builtin_amdgcn_exp2f(m_ - mnew);
            m_ = mnew;
            l_ *= alpha;
            float ar[4];
#pragma unroll
            for (int r = 0; r < 4; r++) ar[r] = __shfl(alpha, (quad << 2) + r);
#pragma unroll
            for (int nt = 0; nt < 4; nt++) {
#pragma unroll
                for (int r = 0; r < 4; r++) O0a[nt][r] *= ar[r];
                if constexpr (NV == 2)
#pragma unroll
                    for (int r = 0; r < 4; r++) O1a[nt][r] *= ar[r];
            }
        }
        float rsum = 0.f;
#pragma unroll
        for (int mt = 0; mt < 4; mt++) {
            float p0 = __builtin_amdgcn_exp2f(accS[mt][0] - m_);
            float p1 = __builtin_amdgcn_exp2f(accS[mt][1] - m_);
            float p2 = __builtin_amdgcn_exp2f(accS[mt][2] - m_);
            float p3 = __builtin_amdgcn_exp2f(accS[mt][3] - m_);
            rsum += (p0 + p1) + (p2 + p3);
            uint2 u;
            u.x = (unsigned int)f2b(p0) | ((unsigned int)f2b(p1) << 16);
            u.y = (unsigned int)f2b(p2) | ((unsigned int)f2b(p3) << 16);
            const int phys = (2 * mt + (quad >> 1)) ^ (n16 & 7);
            *(uint2*)&sP[prow * 64 + (phys << 3) + 4 * (quad & 1)] = u;
        }
        rsum += __shfl_xor(rsum, 16);
        rsum += __shfl_xor(rsum, 32);
        l_ += rsum;

        // ---- PV: plain bf16, 1 MFMA per fragment
#pragma unroll
        for (int s = 0; s < 2; s++) {
            short8 Pf = *(const short8*)&sP[prow * 64 + (((4*s + quad) ^ (n16 & 7)) << 3)];
#pragma unroll
            for (int nt = 0; nt < 4; nt++) {
                const int d = 16 * nt + n16;
                const int phys = (4*s + quad) ^ ((d ^ (d >> 2)) & 7);
                short8 vf = *(const short8*)&sVb0[d * 64 + (phys << 3)];
                O0a[nt] = MFMA_BF16(Pf, vf, O0a[nt], 0, 0, 0);
                if constexpr (NV == 2) {
                    short8 vf1 = *(const short8*)&sV1[d * 64 + (phys << 3)];
                    O1a[nt] = MFMA_BF16(Pf, vf1, O1a[nt], 0, 0, 0);
                }
            }
        }

        __builtin_amdgcn_s_barrier();      // frees buf (and sV for !VIMG)
        __builtin_amdgcn_sched_barrier(0);
        if constexpr (VIMG) {
            if (j0 < N_ - 128) {           // issue tile t+2 into buf just freed
                const int jn = j0 + 128;
                const unsigned short* kg = kg_base + (size_t)jn * k_rs;
                unsigned short* dK = &sK[buf * 8192 + w * 512];
                gll16(kg, dK);
                gll16(kg + (size_t)32 * k_rs, dK + 4096);
                gll16(Vus + (size_t)(jn >> 6) * 4096 + t * 8, &sV0[buf * 4096 + w * 512]);
            }
            __builtin_amdgcn_sched_barrier(0);
        }
        buf ^= 1;
    }

    // ---- epilogue
    float linv[4];
#pragma unroll
    for (int r = 0; r < 4; r++) linv[r] = 1.0f / __shfl(l_, (quad << 2) + r);

    if constexpr (IMGO) {
        // Build pre-swizzled V-image in sP (2 x 64-token blocks), store linear.
        __syncthreads();   // all waves done with sP/main loop
#pragma unroll
        for (int r = 0; r < 4; r++) {
            const int row = i0 + 16 * w + 4 * quad + r;
            const int jj = (16 * w + 4 * quad + r) & 63;
            const int jg = jj >> 3, j7 = jj & 7;
#pragma unroll
            for (int nt = 0; nt < 4; nt++) {
                const int d = 16 * nt + n16;
                const int swd = (d ^ (d >> 2)) & 7;
                float v = O0a[nt][r] * linv[r];
                if constexpr (RESID) v += V0g[(size_t)row * v_sr + d];
                sP[(w >> 2) * 4096 + d * 64 + ((jg ^ swd) << 3) + j7] = f2b(v);
            }
        }
        __syncthreads();
        {
            unsigned short* dst = img0 + (size_t)qt * 8192 + t * 16;
            *(uint4*)dst       = *(const uint4*)&sP[t * 16];
            *(uint4*)(dst + 8) = *(const uint4*)&sP[t * 16 + 8];
        }
        if constexpr (NV == 2) {
            __syncthreads();
#pragma unroll
            for (int r = 0; r < 4; r++) {
                const int row = i0 + 16 * w + 4 * quad + r;
                const int jj = (16 * w + 4 * quad + r) & 63;
                const int jg = jj >> 3, j7 = jj & 7;
#pragma unroll
                for (int nt = 0; nt < 4; nt++) {
                    const int d = 16 * nt + n16;
                    const int swd = (d ^ (d >> 2)) & 7;
                    float v = O1a[nt][r] * linv[r];
                    if constexpr (RESID) v += V1g[(size_t)row * v_sr + d];
                    sP[(w >> 2) * 4096 + d * 64 + ((jg ^ swd) << 3) + j7] = f2b(v);
                }
            }
            __syncthreads();
            unsigned short* dst = img1 + (size_t)qt * 8192 + t * 16;
            *(uint4*)dst       = *(const uint4*)&sP[t * 16];
            *(uint4*)(dst + 8) = *(const uint4*)&sP[t * 16 + 8];
        }
    } else {
#pragma unroll
        for (int r = 0; r < 4; r++) {
            const int row = i0 + 16 * w + 4 * quad + r;
#pragma unroll
            for (int nt = 0; nt < 4; nt++) {
                const int col = 16 * nt + n16;
                float v = O0a[nt][r] * linv[r];
                if constexpr (PACKO)
                    ((unsigned int*)O0g)[(size_t)row * o_sr + col] = packsplit(v);
                else
                    O0g[(size_t)row * o_sr + col] = v;
                if constexpr (NV == 2) {
                    float v1 = O1a[nt][r] * linv[r];
                    if constexpr (PACKO)
                        ((unsigned int*)O1g)[(size_t)row * o_sr + col] = packsplit(v1);
                    else
                        O1g[(size_t)row * o_sr + col] = v1;
                }
            }
        }
    }
}

// ---------------------------------------------------------------------------
extern "C" void kernel_launch(void* const* d_in, const int* in_sizes, int n_in,
                              void* d_out, int out_size, void* d_ws, size_t ws_size,
                              hipStream_t stream)
{
    const float* x1    = (const float*)d_in[0];
    const float* x2    = (const float*)d_in[1];
    const float* Wqkv1 = (const float*)d_in[2];
    const float* Wqkv2 = (const float*)d_in[3];
    const float* Wout1 = (const float*)d_in[4];
    const float* bout1 = (const float*)d_in[5];
    const float* Wout2 = (const float*)d_in[6];
    const float* bout2 = (const float*)d_in[7];
    const float* convw = (const float*)d_in[8];
    const float* convb = (const float*)d_in[9];

    const size_t QKV_ELEMS = (size_t)M_ * QKVC;
    const size_t BND_ELEMS = (size_t)M_ * INNER_;
    if (ws_size < (2 * QKV_ELEMS + 5 * BND_ELEMS) * sizeof(float)) return;

    float* ws   = (float*)d_ws;
    float* qkv1 = ws;
    float* qkv2 = qkv1 + QKV_ELEMS;
    float* MSg  = qkv2 + QKV_ELEMS;
    float* u1   = MSg + BND_ELEMS;
    float* u2   = u1 + BND_ELEMS;
    float* t1m  = u2 + BND_ELEMS;
    float* t2m  = t1m + BND_ELEMS;

    // Aliased buffers (time-disjoint):
    unsigned short* x1t   = (unsigned short*)t1m;  // tiled A image, consumed step 1
    unsigned short* x2t   = (unsigned short*)t2m;  // tiled A image, consumed step 1
    unsigned short* KimgA = (unsigned short*)t1m;  // attn-A K-image, step 2 -> 3
    unsigned short* w1t   = (unsigned short*)u2;   // tiled B images, consumed step 1
    unsigned short* w2t   = w1t + (size_t)QKVC * DIM_ * 2;
    unsigned short* u1img = (unsigned short*)u1;   // V-image, step 3 -> 4
    unsigned short* u2img = (unsigned short*)u2;
    unsigned int*   wo1pt = (unsigned int*)u1;     // packed after u1's last read
    unsigned int*   wo2pt = wo1pt + (size_t)DIM_ * DIM_;

    dim3 blk(256);

    // 0) pack activations + qkv weights into pre-swizzled tiled planar images
    pack_a_tiled<<<dim3(M_ * DIM_ / 1024), blk, 0, stream>>>(x1, x1t);
    pack_a_tiled<<<dim3(M_ * DIM_ / 1024), blk, 0, stream>>>(x2, x2t);
    pack_w_tiled<<<dim3(QKVC / 256, DIM_ / 4), blk, 0, stream>>>(Wqkv1, w1t, QKVC);
    pack_w_tiled<<<dim3(QKVC / 256, DIM_ / 4), blk, 0, stream>>>(Wqkv2, w2t, QKVC);

    // 1) QKV projections; k-slice cols [512,1024) written as planar K-image
    gemm_gll<false, true><<<dim3(QKVC / 128, M_ / 128), blk, 0, stream>>>(
        x1t, w1t, nullptr, qkv1, M_, QKVC);
    gemm_gll<false, true><<<dim3(QKVC / 128, M_ / 128), blk, 0, stream>>>(
        x2t, w2t, nullptr, qkv2, M_, QKVC);

    // 2) conv + sigmoid gate -> MSg (f32) + planar K-image for attn A
    convgate_kernel<<<dim3(M_), dim3(128), 0, stream>>>(qkv1, qkv2, convw, convb,
                                                        MSg, KimgA);

    // Stride descriptors
    const long long msg_sb = (long long)N_ * INNER_, msg_sh = HD_;
    const int       msg_sr = INNER_;
    const long long qkv_sb = (long long)N_ * QKVC, qkv_sh = HD_;
    const int       qkv_sr = QKVC;
    // K-image strides (ushort units)
    const long long kA_sb = (long long)8 * N_ * 128, kA_sh = (long long)N_ * 128;
    const long long kB_sb = (long long)N_ * QKVC * 2;
    // V-image / O-image strides (ushort units)
    const long long vi_sb = (long long)H_ * N_ * HD_, vi_sh = (long long)N_ * HD_;

    // 3) Attention A: K = KimgA, Q = MSg, V = qkv v-slices (f32), +resid
    //    outputs u1,u2 as pre-swizzled bf16 V-images
    mattn_kernel<2, true, false, true, false, 1><<<dim3(512), dim3(512), 0, stream>>>(
        MSg, nullptr, KimgA, nullptr,
        qkv1 + 2 * INNER_, nullptr, qkv2 + 2 * INNER_, nullptr,
        (float*)u1img, nullptr, (float*)u2img, nullptr,
        msg_sb, msg_sh, msg_sr,
        kA_sb, kA_sh, 128, 64,
        qkv_sb, qkv_sh, qkv_sr,
        vi_sb, vi_sh, HD_);

    // 4) Attention B merged pair: K = qkv k-slice planar image, V = u images,
    //    out packed u32 into t1m/t2m
    mattn_kernel<1, false, true, false, true, 2><<<dim3(1024), dim3(512), 0, stream>>>(
        qkv1, qkv2,
        (const unsigned short*)qkv1 + 1024, (const unsigned short*)qkv2 + 1024,
        (const float*)u1img, (const float*)u2img, nullptr, nullptr,
        t1m, t2m, nullptr, nullptr,
        qkv_sb, qkv_sh, qkv_sr,
        kB_sb, 64, QKVC * 2, 512,
        vi_sb, vi_sh, HD_,
        msg_sb, msg_sh, msg_sr);

    // 4.5) pack output weights into u1 (u1's last reader was step 4)
    pack_wt<<<dim3(DIM_ / 256, DIM_ / 4), blk, 0, stream>>>(Wout1, wo1pt, DIM_);
    pack_wt<<<dim3(DIM_ / 256, DIM_ / 4), blk, 0, stream>>>(Wout2, wo2pt, DIM_);

    // 5) Output projections (MFMA, bias, f32 out) — reg-staged path
    float* out1 = (float*)d_out;
    float* out2 = out1 + (size_t)M_ * DIM_;
    gemm_mfma<true><<<dim3(DIM_ / 128, M_ / 128), blk, 0, stream>>>(
        (const unsigned int*)t1m, wo1pt, bout1, out1, M_, DIM_);
    gemm_mfma<true><<<dim3(DIM_ / 128, M_ / 128), blk, 0, stream>>>(
        (const unsigned int*)t2m, wo2pt, bout2, out2, M_, DIM_);
}

// Round 5
// 500.091 us; speedup vs baseline: 1.0633x; 1.0633x over previous
//
#include <hip/hip_runtime.h>
#include <hip/hip_bf16.h>

// Problem constants
#define B_     8
#define N_     1024
#define DIM_   512
#define H_     8
#define HD_    64
#define INNER_ 512
#define QKVC   2048   // 4*INNER
#define M_     8192   // B*N

typedef __attribute__((ext_vector_type(8))) short short8;
typedef __attribute__((ext_vector_type(4))) float f32x4;
#define MFMA_BF16 __builtin_amdgcn_mfma_f32_16x16x32_bf16

__device__ __forceinline__ unsigned short f2b(float x) {
    __hip_bfloat16 h = __float2bfloat16(x);
    unsigned short u; __builtin_memcpy(&u, &h, 2); return u;
}
// pack bf16 hi/lo split of x into one u32: (hi<<16)|lo
__device__ __forceinline__ unsigned int packsplit(float x) {
    unsigned int hb = f2b(x);
    float fh = __uint_as_float(hb << 16);
    unsigned int lb = f2b(x - fh);
    return (hb << 16) | lb;
}
__device__ __forceinline__ void split8(const float* v, short8& h, short8& l) {
#pragma unroll
    for (int i = 0; i < 8; i++) {
        unsigned int hb = f2b(v[i]);
        float fh = __uint_as_float(hb << 16);
        h[i] = (short)hb; l[i] = (short)f2b(v[i] - fh);
    }
}
// hi/lo split of two floats -> packed u32s (ushort order: a in low, b in high)
__device__ __forceinline__ void split2x2(float a, float b, unsigned int& h, unsigned int& l) {
    unsigned int ha = f2b(a), hb = f2b(b);
    float fa = __uint_as_float(ha << 16), fb = __uint_as_float(hb << 16);
    h = ha | (hb << 16);
    l = (unsigned int)f2b(a - fa) | ((unsigned int)f2b(b - fb) << 16);
}

// async global->LDS, 16B per lane, LDS dest = wave-uniform base + lane*16
__device__ __forceinline__ void gll16(const unsigned short* g, unsigned short* l) {
    __builtin_amdgcn_global_load_lds(
        (const __attribute__((address_space(1))) void*)g,
        (__attribute__((address_space(3))) void*)l, 16, 0, 0);
}

// ---------------------------------------------------------------------------
// K-image row format (shared by producers and mattn's sK):
// per token row j: 128 ushorts = 16 chunks of 8; dim d, plane p (0=hi,1=lo)
// lives at chunk ((d>>3)|(p<<3)) ^ (j&15), position d&7 within chunk.
// V image: per (b,h), 16 blocks of 64 tokens; each block is the EXACT sV
// LDS image (4096 ushorts): idx = d*64 + (((j>>3) ^ ((d^(d>>2))&7))<<3)
// + (j&7). Consumer stages with ONE linear gll16 per thread.
// ---------------------------------------------------------------------------

// ---------------------------------------------------------------------------
// Tiled-swizzled planar pack (pre-computed LDS image) for the GEMM.
// Tile (rt, kt) = 16KB = 8192 ushorts at base + (rt*16 + kt)*8192.
// ---------------------------------------------------------------------------
__global__ __launch_bounds__(256)
void pack_a_tiled(const float* __restrict__ in, unsigned short* __restrict__ out)
{
    size_t i = ((size_t)blockIdx.x * 256 + threadIdx.x) * 4;   // element idx, K=512 cols
    float4 v = *(const float4*)(in + i);
    const size_t R = i >> 9;          // row
    const int k  = (int)(i & 511);    // col (multiple of 4)
    const int kt = k >> 5, kk = k & 31;
    const int r  = (int)(R & 127);
    const size_t rt = R >> 7;
    unsigned short* tile = out + (((rt << 4) + kt) << 13) + r * 64;
    unsigned int h01, l01, h23, l23;
    split2x2(v.x, v.y, h01, l01);
    split2x2(v.z, v.w, h23, l23);
    uint2 hv; hv.x = h01; hv.y = h23;
    uint2 lv; lv.x = l01; lv.y = l23;
    const int s7 = r & 7;
    *(uint2*)&tile[(((kk >> 3)     ^ s7) << 3) + (kk & 7)] = hv;
    *(uint2*)&tile[((((kk >> 3)+4) ^ s7) << 3) + (kk & 7)] = lv;
}

// W[k][n] (f32, K=512 rows, N cols) -> B^T tiled-swizzled image (rows = n)
__global__ __launch_bounds__(256)
void pack_w_tiled(const float* __restrict__ W, unsigned short* __restrict__ out, int N)
{
    const int n  = blockIdx.x * 256 + threadIdx.x;
    const int k0 = blockIdx.y * 4;
    float f0 = W[(size_t)(k0 + 0) * N + n];
    float f1 = W[(size_t)(k0 + 1) * N + n];
    float f2 = W[(size_t)(k0 + 2) * N + n];
    float f3 = W[(size_t)(k0 + 3) * N + n];
    const int r  = n & 127;
    const size_t rt = n >> 7;
    const int kt = k0 >> 5, kk = k0 & 31;
    unsigned short* tile = out + (((rt << 4) + kt) << 13) + r * 64;
    unsigned int h01, l01, h23, l23;
    split2x2(f0, f1, h01, l01);
    split2x2(f2, f3, h23, l23);
    uint2 hv; hv.x = h01; hv.y = h23;
    uint2 lv; lv.x = l01; lv.y = l23;
    const int s7 = r & 7;
    *(uint2*)&tile[(((kk >> 3)     ^ s7) << 3) + (kk & 7)] = hv;
    *(uint2*)&tile[((((kk >> 3)+4) ^ s7) << 3) + (kk & 7)] = lv;
}

// Old format pack (kept for out-proj GEMM): W[k][n] -> Wt[n][k] packed u32
__global__ __launch_bounds__(256)
void pack_wt(const float* __restrict__ W, unsigned int* __restrict__ Wt, int N)
{
    const int n = blockIdx.x * 256 + threadIdx.x;
    const int k0 = blockIdx.y * 4;
    uint4 p;
    p.x = packsplit(W[(size_t)(k0 + 0) * N + n]);
    p.y = packsplit(W[(size_t)(k0 + 1) * N + n]);
    p.z = packsplit(W[(size_t)(k0 + 2) * N + n]);
    p.w = packsplit(W[(size_t)(k0 + 3) * N + n]);
    *(uint4*)&Wt[(size_t)n * 512 + k0] = p;
}

// ---------------------------------------------------------------------------
// MFMA split-GEMM with global_load_lds staging from pre-swizzled tiled
// planar inputs. K fixed = 512 (16 k-tiles of 32). 128x128 tile, 4 waves.
// PACKK: k-slice cols [512,1024) written as the strided K-image (hi/lo
// ushorts in mattn's sK bit-layout) into the same dead region of qkv.
// ---------------------------------------------------------------------------
template<bool BIAS, bool PACKK>
__global__ __launch_bounds__(256)
void gemm_gll(const unsigned short* __restrict__ At, const unsigned short* __restrict__ Bt,
              const float* __restrict__ bias, float* __restrict__ Cp,
              int M, int N)
{
    __shared__ __align__(16) unsigned short sA[128 * 64];
    __shared__ __align__(16) unsigned short sB[128 * 64];

    const int t    = threadIdx.x;
    const int lane = t & 63;
    const int w    = t >> 6;
    const int n16  = lane & 15, quad = lane >> 4;
    const int wm   = w >> 1, wn = w & 1;
    const int m0 = blockIdx.y * 128, n0 = blockIdx.x * 128;

    f32x4 acc[4][4];
#pragma unroll
    for (int mt = 0; mt < 4; mt++)
#pragma unroll
        for (int nt = 0; nt < 4; nt++) acc[mt][nt] = (f32x4){0.f, 0.f, 0.f, 0.f};

    // per-lane global source (ushort units); LDS dest wave-uniform
    const unsigned short* Ag = At + ((size_t)blockIdx.y << 4) * 8192 + (w * 64 + lane) * 8;
    const unsigned short* Bg = Bt + ((size_t)blockIdx.x << 4) * 8192 + (w * 64 + lane) * 8;
    unsigned short* sAw = &sA[w * 512];
    unsigned short* sBw = &sB[w * 512];

    for (int kt = 0; kt < 16; kt++) {
        __syncthreads();
        const size_t ko = (size_t)kt * 8192;
#pragma unroll
        for (int i = 0; i < 4; i++) {
            gll16(Ag + ko + i * 2048, sAw + i * 2048);
            gll16(Bg + ko + i * 2048, sBw + i * 2048);
        }
        __syncthreads();   // compiler emits vmcnt(0) drain before s_barrier

        short8 Ah[4], Al[4];
#pragma unroll
        for (int mt = 0; mt < 4; mt++) {
            const int row = 64 * wm + 16 * mt + n16;
            const int base = row * 64;
            const int s7 = row & 7;
            Ah[mt] = *(const short8*)&sA[base + (((quad    ) ^ s7) << 3)];
            Al[mt] = *(const short8*)&sA[base + (((quad + 4) ^ s7) << 3)];
        }
#pragma unroll
        for (int nt = 0; nt < 4; nt++) {
            const int row = 64 * wn + 16 * nt + n16;
            const int base = row * 64;
            const int s7 = row & 7;
            short8 Bh = *(const short8*)&sB[base + (((quad    ) ^ s7) << 3)];
            short8 Bl = *(const short8*)&sB[base + (((quad + 4) ^ s7) << 3)];
#pragma unroll
            for (int mt = 0; mt < 4; mt++) {
                acc[mt][nt] = MFMA_BF16(Ah[mt], Bh, acc[mt][nt], 0, 0, 0);
                acc[mt][nt] = MFMA_BF16(Al[mt], Bh, acc[mt][nt], 0, 0, 0);
                acc[mt][nt] = MFMA_BF16(Ah[mt], Bl, acc[mt][nt], 0, 0, 0);
            }
        }
    }

    const bool packout = PACKK && ((n0 >> 9) == 1);   // qkv k-slice cols
    float bv[4];
#pragma unroll
    for (int nt = 0; nt < 4; nt++)
        bv[nt] = BIAS ? bias[n0 + 64 * wn + 16 * nt + n16] : 0.f;
#pragma unroll
    for (int mt = 0; mt < 4; mt++) {
        const int rbase = m0 + 64 * wm + 16 * mt + 4 * quad;
#pragma unroll
        for (int r = 0; r < 4; r++) {
#pragma unroll
            for (int nt = 0; nt < 4; nt++) {
                const int col = n0 + 64 * wn + 16 * nt + n16;
                const int row = rbase + r;
                const float v = acc[mt][nt][r] + bv[nt];
                if (packout) {
                    // K-image write: hi/lo ushorts, chunk ((d>>3)|plane8)^(j&15)
                    const int hh = (col >> 6) & 7, dd = col & 63, r15 = row & 15;
                    unsigned int hb = f2b(v);
                    float fh = __uint_as_float(hb << 16);
                    unsigned short lb = f2b(v - fh);
                    unsigned short* kim = (unsigned short*)Cp
                        + (size_t)row * (2 * N) + 1024 + hh * 128 + (dd & 7);
                    kim[(((dd >> 3)    ) ^ r15) << 3] = (unsigned short)hb;
                    kim[(((dd >> 3) | 8) ^ r15) << 3] = lb;
                } else {
                    Cp[(size_t)row * N + col] = v;
                }
            }
        }
    }
}

// ---------------------------------------------------------------------------
// OLD register-staged split-GEMM (kept for out-proj: A comes packed u32 from
// the attention epilogue).
// ---------------------------------------------------------------------------
template<bool BIAS>
__global__ __launch_bounds__(256)
void gemm_mfma(const unsigned int* __restrict__ Ap, const unsigned int* __restrict__ Btp,
               const float* __restrict__ bias, float* __restrict__ Cp,
               int M, int N)
{
    const int K = 512;
    __shared__ __align__(16) unsigned short sA[128 * 64];
    __shared__ __align__(16) unsigned short sB[128 * 64];

    const int t    = threadIdx.x;
    const int lane = t & 63;
    const int w    = t >> 6;
    const int n16  = lane & 15, quad = lane >> 4;
    const int wm   = w >> 1, wn = w & 1;
    const int m0 = blockIdx.y * 128, n0 = blockIdx.x * 128;

    f32x4 acc[4][4];
#pragma unroll
    for (int mt = 0; mt < 4; mt++)
#pragma unroll
        for (int nt = 0; nt < 4; nt++) acc[mt][nt] = (f32x4){0.f, 0.f, 0.f, 0.f};

    const int srow = t >> 1;
    const int kb   = (t & 1) * 16;
    const unsigned int* ag = Ap  + (size_t)(m0 + srow) * K + kb;
    const unsigned int* bg = Btp + (size_t)(n0 + srow) * K + kb;
    const int s7s = srow & 7;
    unsigned short* swA = &sA[srow * 64];
    unsigned short* swB = &sB[srow * 64];

    for (int k0 = 0; k0 < K; k0 += 32) {
        __syncthreads();
#pragma unroll
        for (int i = 0; i < 4; i++) {
            const int kk = kb + i * 4;
            const int ch = kk >> 3;
            const int ho = kk & 4;
            const int c_hi = ((ch    ) ^ s7s) << 3;
            const int c_lo = ((ch + 4) ^ s7s) << 3;
            uint4 va = *(const uint4*)(ag + k0 + i * 4);
            uint4 vb = *(const uint4*)(bg + k0 + i * 4);
            uint2 ha, la, hb, lb;
            ha.x = (va.y & 0xFFFF0000u) | (va.x >> 16);
            ha.y = (va.w & 0xFFFF0000u) | (va.z >> 16);
            la.x = (va.y << 16) | (va.x & 0xFFFFu);
            la.y = (va.w << 16) | (va.z & 0xFFFFu);
            hb.x = (vb.y & 0xFFFF0000u) | (vb.x >> 16);
            hb.y = (vb.w & 0xFFFF0000u) | (vb.z >> 16);
            lb.x = (vb.y << 16) | (vb.x & 0xFFFFu);
            lb.y = (vb.w << 16) | (vb.z & 0xFFFFu);
            *(uint2*)&swA[c_hi + ho] = ha;
            *(uint2*)&swA[c_lo + ho] = la;
            *(uint2*)&swB[c_hi + ho] = hb;
            *(uint2*)&swB[c_lo + ho] = lb;
        }
        __syncthreads();

        short8 Ah[4], Al[4];
#pragma unroll
        for (int mt = 0; mt < 4; mt++) {
            const int row = 64 * wm + 16 * mt + n16;
            const int base = row * 64;
            const int s7 = row & 7;
            Ah[mt] = *(const short8*)&sA[base + (((quad    ) ^ s7) << 3)];
            Al[mt] = *(const short8*)&sA[base + (((quad + 4) ^ s7) << 3)];
        }
#pragma unroll
        for (int nt = 0; nt < 4; nt++) {
            const int row = 64 * wn + 16 * nt + n16;
            const int base = row * 64;
            const int s7 = row & 7;
            short8 Bh = *(const short8*)&sB[base + (((quad    ) ^ s7) << 3)];
            short8 Bl = *(const short8*)&sB[base + (((quad + 4) ^ s7) << 3)];
#pragma unroll
            for (int mt = 0; mt < 4; mt++) {
                acc[mt][nt] = MFMA_BF16(Ah[mt], Bh, acc[mt][nt], 0, 0, 0);
                acc[mt][nt] = MFMA_BF16(Al[mt], Bh, acc[mt][nt], 0, 0, 0);
                acc[mt][nt] = MFMA_BF16(Ah[mt], Bl, acc[mt][nt], 0, 0, 0);
            }
        }
    }

    float bv[4];
#pragma unroll
    for (int nt = 0; nt < 4; nt++)
        bv[nt] = BIAS ? bias[n0 + 64 * wn + 16 * nt + n16] : 0.f;
#pragma unroll
    for (int mt = 0; mt < 4; mt++) {
        const int rbase = m0 + 64 * wm + 16 * mt + 4 * quad;
#pragma unroll
        for (int r = 0; r < 4; r++) {
#pragma unroll
            for (int nt = 0; nt < 4; nt++) {
                const int col = n0 + 64 * wn + 16 * nt + n16;
                Cp[(size_t)(rbase + r) * N + col] = acc[mt][nt][r] + bv[nt];
            }
        }
    }
}

// ---------------------------------------------------------------------------
// Depthwise conv (k=5, pad=2) + sigmoid gate. Writes MSg (f32) + blocked
// K-image (hi/lo ushorts in mattn's sK layout) for attention A.
// ---------------------------------------------------------------------------
__global__ __launch_bounds__(128)
void convgate_kernel(const float* __restrict__ qkv1, const float* __restrict__ qkv2,
                     const float* __restrict__ convw,
                     const float* __restrict__ convb,
                     float* __restrict__ MSg, unsigned short* __restrict__ Kimg)
{
    __shared__ float ms[INNER_];
    const int blk = blockIdx.x;
    const int n = blk & (N_ - 1);
    const int b = blk >> 10;
    const int t = threadIdx.x;

    const float4* q1 = (const float4*)(qkv1 + (size_t)blk * QKVC + 3 * INNER_);
    const float4* q2 = (const float4*)(qkv2 + (size_t)blk * QKVC + 3 * INNER_);
    float4 v1 = q1[t], v2 = q2[t];
    float4 s;
    s.x = v1.x + v2.x; s.y = v1.y + v2.y; s.z = v1.z + v2.z; s.w = v1.w + v2.w;
    *(float4*)&ms[t * 4] = s;
    __syncthreads();

    float w[5];
#pragma unroll
    for (int k = 0; k < 5; k++) w[k] = convw[n * 5 + k];
    const float cb = convb[n];

    float out[4];
#pragma unroll
    for (int ff = 0; ff < 4; ff++) {
        int f = t * 4 + ff;
        float A = cb;
#pragma unroll
        for (int k = 0; k < 5; k++) {
            int idx = f + k - 2;
            if (idx >= 0 && idx < INNER_) A += ms[idx] * w[k];
        }
        float sg = 1.f / (1.f + __expf(-A));
        out[ff] = ms[f] * sg;
    }
    *(float4*)&MSg[(size_t)blk * INNER_ + t * 4] = make_float4(out[0], out[1], out[2], out[3]);

    // K-image write: head h = t>>4 (f=4t), dims d0..d0+3, token row n
    const int h  = t >> 4;
    const int d0 = (4 * t) & 63;
    const int r15 = n & 15;
    unsigned short hs[4], ls[4];
#pragma unroll
    for (int e = 0; e < 4; e++) {
        unsigned int hb = f2b(out[e]);
        float fh = __uint_as_float(hb << 16);
        hs[e] = (unsigned short)hb;
        ls[e] = f2b(out[e] - fh);
    }
    unsigned short* kim = Kimg + ((size_t)(b * 8 + h) * 1024 + n) * 128 + (d0 & 7);
    uint2 hv; hv.x = (unsigned int)hs[0] | ((unsigned int)hs[1] << 16);
              hv.y = (unsigned int)hs[2] | ((unsigned int)hs[3] << 16);
    uint2 lv; lv.x = (unsigned int)ls[0] | ((unsigned int)ls[1] << 16);
              lv.y = (unsigned int)ls[2] | ((unsigned int)ls[3] << 16);
    *(uint2*)&kim[(((d0 >> 3)    ) ^ r15) << 3] = hv;
    *(uint2*)&kim[(((d0 >> 3) | 8) ^ r15) << 3] = lv;
}

// ---------------------------------------------------------------------------
// MFMA flash attention: 512 threads, Q-tile 128, simple 2-barrier loop.
// K staged via global_load_lds from pre-swizzled K-image (zero staging VALU).
// VIMG: V staged via ONE linear gll16 per thread from pre-swizzled V-image.
// IMGO: outputs written as V-images (single extra barrier: sP holds out0
// image, sK (free in epilogue) holds out1 image; linear coalesced stores).
// Softmax in log2 domain (Q pre-scaled by 0.125*log2e) with defer-max.
// ---------------------------------------------------------------------------
template<int NV, bool RESID, bool PACKO, bool IMGO, bool VIMG, int NPROB>
__global__ __launch_bounds__(512, 2)
void mattn_kernel(const float* __restrict__ Q0, const float* __restrict__ Q1,
                  const unsigned short* __restrict__ K0, const unsigned short* __restrict__ K1,
                  const float* __restrict__ VA0, const float* __restrict__ VA1,
                  const float* __restrict__ VB0, const float* __restrict__ VB1,
                  float* __restrict__ OA0, float* __restrict__ OA1,
                  float* __restrict__ OB0, float* __restrict__ OB1,
                  long long q_sb, long long q_sh, int q_sr,
                  long long k_sb, long long k_sh, int k_rs,
                  long long v_sb, long long v_sh, int v_sr,
                  long long o_sb, long long o_sh, int o_sr)
{
    __shared__ __align__(16) unsigned short sK[64 * 128];   // hi|lo planes
    __shared__ __align__(16) unsigned short sV0[64 * 64];   // V^T plain bf16
    __shared__ __align__(16) unsigned short sV1[(NV == 2) ? 64 * 64 : 8];
    __shared__ __align__(16) unsigned short sP[128 * 64];   // P bf16 / epi image

    const int t    = threadIdx.x;
    const int w    = t >> 6;        // wave 0..7
    const int lane = t & 63;
    const int n16  = lane & 15;
    const int quad = lane >> 4;

    // XCD-aware decode
    const int bid = blockIdx.x;
    const int c   = bid & 7;
    const int r1  = bid >> 3;
    const int qt  = r1 & 7;
    const int r2  = r1 >> 3;
    const int g   = r2 & 7;
    const int p   = (NPROB == 2) ? (r2 >> 3) : 0;
    const int bh  = 8 * g + c;
    const int b = bh >> 3, h = bh & 7;
    const int i0 = qt * 128;

    const float* Qb          = (NPROB == 2 && p) ? Q1 : Q0;
    const unsigned short* Kb = (NPROB == 2 && p) ? K1 : K0;
    const float* VAb         = (NPROB == 2 && p) ? VA1 : VA0;
    float* OAb               = (NPROB == 2 && p) ? OA1 : OA0;

    const float* Qg          = Qb  + (size_t)b * q_sb + (size_t)h * q_sh;
    const unsigned short* Kg = Kb  + (size_t)b * k_sb + (size_t)h * k_sh;

    const float* V0g = nullptr;
    const float* V1g = nullptr;
    const unsigned short* Vus = nullptr;
    if constexpr (VIMG) {
        Vus = (const unsigned short*)VAb + (size_t)b * v_sb + (size_t)h * v_sh;
    } else {
        V0g = VAb + (size_t)b * v_sb + (size_t)h * v_sh;
        if constexpr (NV == 2)
            V1g = VB0 + (size_t)b * v_sb + (size_t)h * v_sh;
    }

    float* O0g = nullptr; float* O1g = nullptr;
    unsigned short* img0 = nullptr; unsigned short* img1 = nullptr;
    if constexpr (IMGO) {
        img0 = (unsigned short*)OAb + (size_t)b * o_sb + (size_t)h * o_sh;
        if constexpr (NV == 2)
            img1 = (unsigned short*)OB0 + (size_t)b * o_sb + (size_t)h * o_sh;
    } else {
        O0g = OAb + (size_t)b * o_sb + (size_t)h * o_sh;
        if constexpr (NV == 2)
            O1g = OB0 + (size_t)b * o_sb + (size_t)h * o_sh;
    }

    // persistent Q fragments (hi/lo split), rows i0+16w+n16,
    // pre-scaled by 0.125 * log2(e) so exps are bare v_exp_f32.
    const float SC2 = 0.1803368801f;
    short8 Qh[2], Ql[2];
#pragma unroll
    for (int s = 0; s < 2; s++) {
        const float* qp = Qg + (size_t)(i0 + 16 * w + n16) * q_sr + 32 * s + 8 * quad;
        float qv[8];
        float4 q0 = *(const float4*)qp;
        float4 q1 = *(const float4*)(qp + 4);
        qv[0]=q0.x*SC2; qv[1]=q0.y*SC2; qv[2]=q0.z*SC2; qv[3]=q0.w*SC2;
        qv[4]=q1.x*SC2; qv[5]=q1.y*SC2; qv[6]=q1.z*SC2; qv[7]=q1.w*SC2;
        split8(qv, Qh[s], Ql[s]);
    }

    float m_ = -1e30f, l_ = 0.f;
    f32x4 O0a[4], O1a[(NV == 2) ? 4 : 1];
#pragma unroll
    for (int nt = 0; nt < 4; nt++) O0a[nt] = (f32x4){0.f,0.f,0.f,0.f};
    if constexpr (NV == 2) {
#pragma unroll
        for (int nt = 0; nt < 4; nt++) O1a[nt] = (f32x4){0.f,0.f,0.f,0.f};
    }

    const int prow = 16 * w + n16;          // 0..127
    const int vc = t & 15, vp = t >> 4;     // V f32 staging: d-chunk, j-pair

    // K staging via gll: wave w stages rows {4w+(l>>4)} and +32 (2 passes)
    const unsigned short* kg_base = Kg + (size_t)((w << 2) + (lane >> 4)) * k_rs
                                       + ((lane & 15) << 3);
    unsigned short* sKw = &sK[w * 512];

    for (int j0 = 0; j0 < N_; j0 += 64) {
        __syncthreads();

        // ---- stage K: 2x global_load_lds(16B) from pre-swizzled image
        {
            const unsigned short* kg = kg_base + (size_t)j0 * k_rs;
            gll16(kg, sKw);
            gll16(kg + (size_t)32 * k_rs, sKw + 4096);
        }
        // ---- stage V
        if constexpr (VIMG) {
            gll16(Vus + (size_t)(j0 >> 6) * 4096 + t * 8, &sV0[w * 512]);
        } else {
            const int j = 2 * vp;
            const float* a0 = V0g + (size_t)(j0 + j) * v_sr + 4 * vc;
            float4 va = *(const float4*)a0;
            float4 vb = *(const float4*)(a0 + v_sr);
#pragma unroll
            for (int e = 0; e < 4; e++) {
                float fa = (e==0)?va.x:(e==1)?va.y:(e==2)?va.z:va.w;
                float fb = (e==0)?vb.x:(e==1)?vb.y:(e==2)?vb.z:vb.w;
                unsigned int u = (unsigned int)f2b(fa) | ((unsigned int)f2b(fb) << 16);
                const int d = 4 * vc + e;
                const int phys = (vp >> 2) ^ ((d ^ (d >> 2)) & 7);
                *(unsigned int*)&sV0[d * 64 + (phys << 3) + (j & 7)] = u;
            }
            if constexpr (NV == 2) {
                const float* a1 = V1g + (size_t)(j0 + j) * v_sr + 4 * vc;
                float4 wa = *(const float4*)a1;
                float4 wb = *(const float4*)(a1 + v_sr);
#pragma unroll
                for (int e = 0; e < 4; e++) {
                    float fa = (e==0)?wa.x:(e==1)?wa.y:(e==2)?wa.z:wa.w;
                    float fb = (e==0)?wb.x:(e==1)?wb.y:(e==2)?wb.z:wb.w;
                    unsigned int u = (unsigned int)f2b(fa) | ((unsigned int)f2b(fb) << 16);
                    const int d = 4 * vc + e;
                    const int phys = (vp >> 2) ^ ((d ^ (d >> 2)) & 7);
                    *(unsigned int*)&sV1[d * 64 + (phys << 3) + (j & 7)] = u;
                }
            }
        }
        __syncthreads();   // drains gll vmcnt + V lgkm

        // ---- S^T = K.Q^T, split 3-MFMA, frags straight from planes
        f32x4 accS[4];
#pragma unroll
        for (int mt = 0; mt < 4; mt++) accS[mt] = (f32x4){0.f,0.f,0.f,0.f};
#pragma unroll
        for (int s = 0; s < 2; s++) {
#pragma unroll
            for (int mt = 0; mt < 4; mt++) {
                const unsigned short* kb2 = &sK[(16 * mt + n16) * 128];
                short8 kh = *(const short8*)&kb2[(((4*s + quad)    ) ^ n16) << 3];
                short8 kl = *(const short8*)&kb2[(((4*s + quad) + 8) ^ n16) << 3];
                accS[mt] = MFMA_BF16(kl, Qh[s], accS[mt], 0, 0, 0);
                accS[mt] = MFMA_BF16(kh, Ql[s], accS[mt], 0, 0, 0);
                accS[mt] = MFMA_BF16(kh, Qh[s], accS[mt], 0, 0, 0);
            }
        }

        // ---- online softmax (log2 domain), defer-max, wave-local P store
        float tmax = -1e30f;
#pragma unroll
        for (int mt = 0; mt < 4; mt++)
#pragma unroll
            for (int r = 0; r < 4; r++) tmax = fmaxf(tmax, accS[mt][r]);
        tmax = fmaxf(tmax, __shfl_xor(tmax, 16));
        tmax = fmaxf(tmax, __shfl_xor(tmax, 32));
        if (!__all(tmax <= m_ + 11.0f)) {
            const float mnew = fmaxf(m_, tmax);
            const float alpha = __builtin_amdgcn_exp2f(m_ - mnew);
            m_ = mnew;
            l_ *= alpha;
            float ar[4];
#pragma unroll
            for (int r = 0; r < 4; r++) ar[r] = __shfl(alpha, (quad << 2) + r);
#pragma unroll
            for (int nt = 0; nt < 4; nt++) {
#pragma unroll
                for (int r = 0; r < 4; r++) O0a[nt][r] *= ar[r];
                if constexpr (NV == 2)
#pragma unroll
                    for (int r = 0; r < 4; r++) O1a[nt][r] *= ar[r];
            }
        }
        float rsum = 0.f;
#pragma unroll
        for (int mt = 0; mt < 4; mt++) {
            float p0 = __builtin_amdgcn_exp2f(accS[mt][0] - m_);
            float p1 = __builtin_amdgcn_exp2f(accS[mt][1] - m_);
            float p2 = __builtin_amdgcn_exp2f(accS[mt][2] - m_);
            float p3 = __builtin_amdgcn_exp2f(accS[mt][3] - m_);
            rsum += (p0 + p1) + (p2 + p3);
            uint2 u;
            u.x = (unsigned int)f2b(p0) | ((unsigned int)f2b(p1) << 16);
            u.y = (unsigned int)f2b(p2) | ((unsigned int)f2b(p3) << 16);
            const int phys = (2 * mt + (quad >> 1)) ^ (n16 & 7);
            *(uint2*)&sP[prow * 64 + (phys << 3) + 4 * (quad & 1)] = u;
        }
        rsum += __shfl_xor(rsum, 16);
        rsum += __shfl_xor(rsum, 32);
        l_ += rsum;

        // ---- PV: plain bf16, 1 MFMA per fragment
#pragma unroll
        for (int s = 0; s < 2; s++) {
            short8 Pf = *(const short8*)&sP[prow * 64 + (((4*s + quad) ^ (n16 & 7)) << 3)];
#pragma unroll
            for (int nt = 0; nt < 4; nt++) {
                const int d = 16 * nt + n16;
                const int phys = (4*s + quad) ^ ((d ^ (d >> 2)) & 7);
                short8 vf = *(const short8*)&sV0[d * 64 + (phys << 3)];
                O0a[nt] = MFMA_BF16(Pf, vf, O0a[nt], 0, 0, 0);
                if constexpr (NV == 2) {
                    short8 vf1 = *(const short8*)&sV1[d * 64 + (phys << 3)];
                    O1a[nt] = MFMA_BF16(Pf, vf1, O1a[nt], 0, 0, 0);
                }
            }
        }
    }

    // ---- epilogue
    float linv[4];
#pragma unroll
    for (int r = 0; r < 4; r++) linv[r] = 1.0f / __shfl(l_, (quad << 2) + r);

    if constexpr (IMGO) {
        // Build pre-swizzled V-images: out0 -> sP, out1 -> sK (both free now).
        __syncthreads();
#pragma unroll
        for (int r = 0; r < 4; r++) {
            const int row = i0 + 16 * w + 4 * quad + r;
            const int jj = (16 * w + 4 * quad + r) & 63;
            const int jg = jj >> 3, j7 = jj & 7;
#pragma unroll
            for (int nt = 0; nt < 4; nt++) {
                const int d = 16 * nt + n16;
                const int swd = (d ^ (d >> 2)) & 7;
                const int off = (w >> 2) * 4096 + d * 64 + ((jg ^ swd) << 3) + j7;
                float v = O0a[nt][r] * linv[r];
                if constexpr (RESID) v += V0g[(size_t)row * v_sr + d];
                sP[off] = f2b(v);
                if constexpr (NV == 2) {
                    float v1 = O1a[nt][r] * linv[r];
                    if constexpr (RESID) v1 += V1g[(size_t)row * v_sr + d];
                    sK[off] = f2b(v1);
                }
            }
        }
        __syncthreads();
        {
            unsigned short* dst = img0 + (size_t)qt * 8192 + t * 16;
            *(uint4*)dst       = *(const uint4*)&sP[t * 16];
            *(uint4*)(dst + 8) = *(const uint4*)&sP[t * 16 + 8];
        }
        if constexpr (NV == 2) {
            unsigned short* dst = img1 + (size_t)qt * 8192 + t * 16;
            *(uint4*)dst       = *(const uint4*)&sK[t * 16];
            *(uint4*)(dst + 8) = *(const uint4*)&sK[t * 16 + 8];
        }
    } else {
#pragma unroll
        for (int r = 0; r < 4; r++) {
            const int row = i0 + 16 * w + 4 * quad + r;
#pragma unroll
            for (int nt = 0; nt < 4; nt++) {
                const int col = 16 * nt + n16;
                float v = O0a[nt][r] * linv[r];
                if constexpr (PACKO)
                    ((unsigned int*)O0g)[(size_t)row * o_sr + col] = packsplit(v);
                else
                    O0g[(size_t)row * o_sr + col] = v;
                if constexpr (NV == 2) {
                    float v1 = O1a[nt][r] * linv[r];
                    if constexpr (PACKO)
                        ((unsigned int*)O1g)[(size_t)row * o_sr + col] = packsplit(v1);
                    else
                        O1g[(size_t)row * o_sr + col] = v1;
                }
            }
        }
    }
}

// ---------------------------------------------------------------------------
extern "C" void kernel_launch(void* const* d_in, const int* in_sizes, int n_in,
                              void* d_out, int out_size, void* d_ws, size_t ws_size,
                              hipStream_t stream)
{
    const float* x1    = (const float*)d_in[0];
    const float* x2    = (const float*)d_in[1];
    const float* Wqkv1 = (const float*)d_in[2];
    const float* Wqkv2 = (const float*)d_in[3];
    const float* Wout1 = (const float*)d_in[4];
    const float* bout1 = (const float*)d_in[5];
    const float* Wout2 = (const float*)d_in[6];
    const float* bout2 = (const float*)d_in[7];
    const float* convw = (const float*)d_in[8];
    const float* convb = (const float*)d_in[9];

    const size_t QKV_ELEMS = (size_t)M_ * QKVC;
    const size_t BND_ELEMS = (size_t)M_ * INNER_;
    if (ws_size < (2 * QKV_ELEMS + 5 * BND_ELEMS) * sizeof(float)) return;

    float* ws   = (float*)d_ws;
    float* qkv1 = ws;
    float* qkv2 = qkv1 + QKV_ELEMS;
    float* MSg  = qkv2 + QKV_ELEMS;
    float* u1   = MSg + BND_ELEMS;
    float* u2   = u1 + BND_ELEMS;
    float* t1m  = u2 + BND_ELEMS;
    float* t2m  = t1m + BND_ELEMS;

    // Aliased buffers (time-disjoint):
    unsigned short* x1t   = (unsigned short*)t1m;  // tiled A image, consumed step 1
    unsigned short* x2t   = (unsigned short*)t2m;  // tiled A image, consumed step 1
    unsigned short* KimgA = (unsigned short*)t1m;  // attn-A K-image, step 2 -> 3
    unsigned short* w1t   = (unsigned short*)u2;   // tiled B images, consumed step 1
    unsigned short* w2t   = w1t + (size_t)QKVC * DIM_ * 2;
    unsigned short* u1img = (unsigned short*)u1;   // V-image, step 3 -> 4
    unsigned short* u2img = (unsigned short*)u2;
    unsigned int*   wo1pt = (unsigned int*)u1;     // packed after u1's last read
    unsigned int*   wo2pt = wo1pt + (size_t)DIM_ * DIM_;

    dim3 blk(256);

    // 0) pack activations + qkv weights into pre-swizzled tiled planar images
    pack_a_tiled<<<dim3(M_ * DIM_ / 1024), blk, 0, stream>>>(x1, x1t);
    pack_a_tiled<<<dim3(M_ * DIM_ / 1024), blk, 0, stream>>>(x2, x2t);
    pack_w_tiled<<<dim3(QKVC / 256, DIM_ / 4), blk, 0, stream>>>(Wqkv1, w1t, QKVC);
    pack_w_tiled<<<dim3(QKVC / 256, DIM_ / 4), blk, 0, stream>>>(Wqkv2, w2t, QKVC);

    // 1) QKV projections; k-slice cols [512,1024) written as strided K-image
    gemm_gll<false, true><<<dim3(QKVC / 128, M_ / 128), blk, 0, stream>>>(
        x1t, w1t, nullptr, qkv1, M_, QKVC);
    gemm_gll<false, true><<<dim3(QKVC / 128, M_ / 128), blk, 0, stream>>>(
        x2t, w2t, nullptr, qkv2, M_, QKVC);

    // 2) conv + sigmoid gate -> MSg (f32) + blocked K-image for attn A
    convgate_kernel<<<dim3(M_), dim3(128), 0, stream>>>(qkv1, qkv2, convw, convb,
                                                        MSg, KimgA);

    // Stride descriptors
    const long long msg_sb = (long long)N_ * INNER_, msg_sh = HD_;
    const int       msg_sr = INNER_;
    const long long qkv_sb = (long long)N_ * QKVC, qkv_sh = HD_;
    const int       qkv_sr = QKVC;
    // K-image strides (ushort units)
    const long long kA_sb = (long long)8 * N_ * 128, kA_sh = (long long)N_ * 128;
    const long long kB_sb = (long long)N_ * QKVC * 2, kB_sh = 128;
    // V-image / O-image strides (ushort units)
    const long long vi_sb = (long long)H_ * N_ * HD_, vi_sh = (long long)N_ * HD_;

    // 3) Attention A: K = KimgA, Q = MSg, V = qkv v-slices (f32), +resid
    //    outputs u1,u2 as pre-swizzled bf16 V-images
    mattn_kernel<2, true, false, true, false, 1><<<dim3(512), dim3(512), 0, stream>>>(
        MSg, nullptr, KimgA, nullptr,
        qkv1 + 2 * INNER_, nullptr, qkv2 + 2 * INNER_, nullptr,
        (float*)u1img, nullptr, (float*)u2img, nullptr,
        msg_sb, msg_sh, msg_sr,
        kA_sb, kA_sh, 128,
        qkv_sb, qkv_sh, qkv_sr,
        vi_sb, vi_sh, HD_);

    // 4) Attention B merged pair: K = qkv k-slice image, V = u images (gll),
    //    out packed u32 into t1m/t2m
    mattn_kernel<1, false, true, false, true, 2><<<dim3(1024), dim3(512), 0, stream>>>(
        qkv1, qkv2,
        (const unsigned short*)qkv1 + 1024, (const unsigned short*)qkv2 + 1024,
        (const float*)u1img, (const float*)u2img, nullptr, nullptr,
        t1m, t2m, nullptr, nullptr,
        qkv_sb, qkv_sh, qkv_sr,
        kB_sb, kB_sh, QKVC * 2,
        vi_sb, vi_sh, HD_,
        msg_sb, msg_sh, msg_sr);

    // 4.5) pack output weights into u1 (u1's last reader was step 4)
    pack_wt<<<dim3(DIM_ / 256, DIM_ / 4), blk, 0, stream>>>(Wout1, wo1pt, DIM_);
    pack_wt<<<dim3(DIM_ / 256, DIM_ / 4), blk, 0, stream>>>(Wout2, wo2pt, DIM_);

    // 5) Output projections (MFMA, bias, f32 out) — reg-staged path
    float* out1 = (float*)d_out;
    float* out2 = out1 + (size_t)M_ * DIM_;
    gemm_mfma<true><<<dim3(DIM_ / 128, M_ / 128), blk, 0, stream>>>(
        (const unsigned int*)t1m, wo1pt, bout1, out1, M_, DIM_);
    gemm_mfma<true><<<dim3(DIM_ / 128, M_ / 128), blk, 0, stream>>>(
        (const unsigned int*)t2m, wo2pt, bout2, out2, M_, DIM_);
}

// Round 8
// 465.828 us; speedup vs baseline: 1.1415x; 1.0736x over previous
//
#include <hip/hip_runtime.h>
#include <hip/hip_bf16.h>

// Problem constants
#define B_     8
#define N_     1024
#define DIM_   512
#define H_     8
#define HD_    64
#define INNER_ 512
#define QKVC   2048   // 4*INNER
#define M_     8192   // B*N

typedef __attribute__((ext_vector_type(8))) short short8;
typedef __attribute__((ext_vector_type(4))) float f32x4;
#define MFMA_BF16 __builtin_amdgcn_mfma_f32_16x16x32_bf16

__device__ __forceinline__ unsigned short f2b(float x) {
    __hip_bfloat16 h = __float2bfloat16(x);
    unsigned short u; __builtin_memcpy(&u, &h, 2); return u;
}
// pack bf16 hi/lo split of x into one u32: (hi<<16)|lo
__device__ __forceinline__ unsigned int packsplit(float x) {
    unsigned int hb = f2b(x);
    float fh = __uint_as_float(hb << 16);
    unsigned int lb = f2b(x - fh);
    return (hb << 16) | lb;
}
__device__ __forceinline__ void split8(const float* v, short8& h, short8& l) {
#pragma unroll
    for (int i = 0; i < 8; i++) {
        unsigned int hb = f2b(v[i]);
        float fh = __uint_as_float(hb << 16);
        h[i] = (short)hb; l[i] = (short)f2b(v[i] - fh);
    }
}
// hi/lo split of two floats -> packed u32s (ushort order: a in low, b in high)
__device__ __forceinline__ void split2x2(float a, float b, unsigned int& h, unsigned int& l) {
    unsigned int ha = f2b(a), hb = f2b(b);
    float fa = __uint_as_float(ha << 16), fb = __uint_as_float(hb << 16);
    h = ha | (hb << 16);
    l = (unsigned int)f2b(a - fa) | ((unsigned int)f2b(b - fb) << 16);
}

// async global->LDS, 16B per lane, LDS dest = wave-uniform base + lane*16
__device__ __forceinline__ void gll16(const unsigned short* g, unsigned short* l) {
    __builtin_amdgcn_global_load_lds(
        (const __attribute__((address_space(1))) void*)g,
        (__attribute__((address_space(3))) void*)l, 16, 0, 0);
}

// ---------------------------------------------------------------------------
// Layout notes
//  K planar image: per token row, [hi-plane D ushorts][lo-plane D ushorts].
//    Consumer (mattn) folds the sK chunk swizzle lq = q ^ (row&15) into the
//    per-lane gll SOURCE offset; the global image itself is linear -> both
//    producers (gemm PACKK epilogue, convgate) write coalesced.
// ---------------------------------------------------------------------------

// ---------------------------------------------------------------------------
// Tiled-swizzled planar pack (pre-computed LDS image) for the GEMM.
// Tile (rt, kt) = 16KB = 8192 ushorts at base + (rt*16 + kt)*8192.
// ---------------------------------------------------------------------------
__global__ __launch_bounds__(256)
void pack_a_tiled(const float* __restrict__ in, unsigned short* __restrict__ out)
{
    size_t i = ((size_t)blockIdx.x * 256 + threadIdx.x) * 4;   // element idx, K=512 cols
    float4 v = *(const float4*)(in + i);
    const size_t R = i >> 9;          // row
    const int k  = (int)(i & 511);    // col (multiple of 4)
    const int kt = k >> 5, kk = k & 31;
    const int r  = (int)(R & 127);
    const size_t rt = R >> 7;
    unsigned short* tile = out + (((rt << 4) + kt) << 13) + r * 64;
    unsigned int h01, l01, h23, l23;
    split2x2(v.x, v.y, h01, l01);
    split2x2(v.z, v.w, h23, l23);
    uint2 hv; hv.x = h01; hv.y = h23;
    uint2 lv; lv.x = l01; lv.y = l23;
    const int s7 = r & 7;
    *(uint2*)&tile[(((kk >> 3)     ^ s7) << 3) + (kk & 7)] = hv;
    *(uint2*)&tile[((((kk >> 3)+4) ^ s7) << 3) + (kk & 7)] = lv;
}

// W[k][n] (f32, K=512 rows, N cols) -> B^T tiled-swizzled image (rows = n)
__global__ __launch_bounds__(256)
void pack_w_tiled(const float* __restrict__ W, unsigned short* __restrict__ out, int N)
{
    const int n  = blockIdx.x * 256 + threadIdx.x;
    const int k0 = blockIdx.y * 4;
    float f0 = W[(size_t)(k0 + 0) * N + n];
    float f1 = W[(size_t)(k0 + 1) * N + n];
    float f2 = W[(size_t)(k0 + 2) * N + n];
    float f3 = W[(size_t)(k0 + 3) * N + n];
    const int r  = n & 127;
    const size_t rt = n >> 7;
    const int kt = k0 >> 5, kk = k0 & 31;
    unsigned short* tile = out + (((rt << 4) + kt) << 13) + r * 64;
    unsigned int h01, l01, h23, l23;
    split2x2(f0, f1, h01, l01);
    split2x2(f2, f3, h23, l23);
    uint2 hv; hv.x = h01; hv.y = h23;
    uint2 lv; lv.x = l01; lv.y = l23;
    const int s7 = r & 7;
    *(uint2*)&tile[(((kk >> 3)     ^ s7) << 3) + (kk & 7)] = hv;
    *(uint2*)&tile[((((kk >> 3)+4) ^ s7) << 3) + (kk & 7)] = lv;
}

// Old format pack (kept for out-proj GEMM): W[k][n] -> Wt[n][k] packed u32
__global__ __launch_bounds__(256)
void pack_wt(const float* __restrict__ W, unsigned int* __restrict__ Wt, int N)
{
    const int n = blockIdx.x * 256 + threadIdx.x;
    const int k0 = blockIdx.y * 4;
    uint4 p;
    p.x = packsplit(W[(size_t)(k0 + 0) * N + n]);
    p.y = packsplit(W[(size_t)(k0 + 1) * N + n]);
    p.z = packsplit(W[(size_t)(k0 + 2) * N + n]);
    p.w = packsplit(W[(size_t)(k0 + 3) * N + n]);
    *(uint4*)&Wt[(size_t)n * 512 + k0] = p;
}

// ---------------------------------------------------------------------------
// MFMA split-GEMM, global_load_lds staging from pre-swizzled tiled inputs.
// PACKK: k-slice cols [512,1024) written as PLANAR hi/lo ushorts into the
// dead k region of the qkv row (coalesced 32B segments per 16 lanes).
// ---------------------------------------------------------------------------
template<bool BIAS, bool PACKK>
__global__ __launch_bounds__(256)
void gemm_gll(const unsigned short* __restrict__ At, const unsigned short* __restrict__ Bt,
              const float* __restrict__ bias, float* __restrict__ Cp,
              int M, int N)
{
    __shared__ __align__(16) unsigned short sA[128 * 64];
    __shared__ __align__(16) unsigned short sB[128 * 64];

    const int t    = threadIdx.x;
    const int lane = t & 63;
    const int w    = t >> 6;
    const int n16  = lane & 15, quad = lane >> 4;
    const int wm   = w >> 1, wn = w & 1;
    const int m0 = blockIdx.y * 128, n0 = blockIdx.x * 128;

    f32x4 acc[4][4];
#pragma unroll
    for (int mt = 0; mt < 4; mt++)
#pragma unroll
        for (int nt = 0; nt < 4; nt++) acc[mt][nt] = (f32x4){0.f, 0.f, 0.f, 0.f};

    const unsigned short* Ag = At + ((size_t)blockIdx.y << 4) * 8192 + (w * 64 + lane) * 8;
    const unsigned short* Bg = Bt + ((size_t)blockIdx.x << 4) * 8192 + (w * 64 + lane) * 8;
    unsigned short* sAw = &sA[w * 512];
    unsigned short* sBw = &sB[w * 512];

    for (int kt = 0; kt < 16; kt++) {
        __syncthreads();
        const size_t ko = (size_t)kt * 8192;
#pragma unroll
        for (int i = 0; i < 4; i++) {
            gll16(Ag + ko + i * 2048, sAw + i * 2048);
            gll16(Bg + ko + i * 2048, sBw + i * 2048);
        }
        __syncthreads();

        short8 Ah[4], Al[4];
#pragma unroll
        for (int mt = 0; mt < 4; mt++) {
            const int row = 64 * wm + 16 * mt + n16;
            const int base = row * 64;
            const int s7 = row & 7;
            Ah[mt] = *(const short8*)&sA[base + (((quad    ) ^ s7) << 3)];
            Al[mt] = *(const short8*)&sA[base + (((quad + 4) ^ s7) << 3)];
        }
#pragma unroll
        for (int nt = 0; nt < 4; nt++) {
            const int row = 64 * wn + 16 * nt + n16;
            const int base = row * 64;
            const int s7 = row & 7;
            short8 Bh = *(const short8*)&sB[base + (((quad    ) ^ s7) << 3)];
            short8 Bl = *(const short8*)&sB[base + (((quad + 4) ^ s7) << 3)];
#pragma unroll
            for (int mt = 0; mt < 4; mt++) {
                acc[mt][nt] = MFMA_BF16(Ah[mt], Bh, acc[mt][nt], 0, 0, 0);
                acc[mt][nt] = MFMA_BF16(Al[mt], Bh, acc[mt][nt], 0, 0, 0);
                acc[mt][nt] = MFMA_BF16(Ah[mt], Bl, acc[mt][nt], 0, 0, 0);
            }
        }
    }

    const bool packout = PACKK && ((n0 >> 9) == 1);   // qkv k-slice cols
    float bv[4];
#pragma unroll
    for (int nt = 0; nt < 4; nt++)
        bv[nt] = BIAS ? bias[n0 + 64 * wn + 16 * nt + n16] : 0.f;
#pragma unroll
    for (int mt = 0; mt < 4; mt++) {
        const int rbase = m0 + 64 * wm + 16 * mt + 4 * quad;
#pragma unroll
        for (int r = 0; r < 4; r++) {
#pragma unroll
            for (int nt = 0; nt < 4; nt++) {
                const int col = n0 + 64 * wn + 16 * nt + n16;
                const int row = rbase + r;
                const float v = acc[mt][nt][r] + bv[nt];
                if (packout) {
                    // planar K-image: hi at [1024+dg], lo at [1536+dg]
                    const int dg = col & 511;
                    unsigned int hb = f2b(v);
                    float fh = __uint_as_float(hb << 16);
                    unsigned short* kim = (unsigned short*)Cp + (size_t)row * (2 * N);
                    kim[1024 + dg] = (unsigned short)hb;
                    kim[1536 + dg] = f2b(v - fh);
                } else {
                    Cp[(size_t)row * N + col] = v;
                }
            }
        }
    }
}

// ---------------------------------------------------------------------------
// OLD register-staged split-GEMM (kept for out-proj: A comes packed u32 from
// the attention epilogue).
// ---------------------------------------------------------------------------
template<bool BIAS>
__global__ __launch_bounds__(256)
void gemm_mfma(const unsigned int* __restrict__ Ap, const unsigned int* __restrict__ Btp,
               const float* __restrict__ bias, float* __restrict__ Cp,
               int M, int N)
{
    const int K = 512;
    __shared__ __align__(16) unsigned short sA[128 * 64];
    __shared__ __align__(16) unsigned short sB[128 * 64];

    const int t    = threadIdx.x;
    const int lane = t & 63;
    const int w    = t >> 6;
    const int n16  = lane & 15, quad = lane >> 4;
    const int wm   = w >> 1, wn = w & 1;
    const int m0 = blockIdx.y * 128, n0 = blockIdx.x * 128;

    f32x4 acc[4][4];
#pragma unroll
    for (int mt = 0; mt < 4; mt++)
#pragma unroll
        for (int nt = 0; nt < 4; nt++) acc[mt][nt] = (f32x4){0.f, 0.f, 0.f, 0.f};

    const int srow = t >> 1;
    const int kb   = (t & 1) * 16;
    const unsigned int* ag = Ap  + (size_t)(m0 + srow) * K + kb;
    const unsigned int* bg = Btp + (size_t)(n0 + srow) * K + kb;
    const int s7s = srow & 7;
    unsigned short* swA = &sA[srow * 64];
    unsigned short* swB = &sB[srow * 64];

    for (int k0 = 0; k0 < K; k0 += 32) {
        __syncthreads();
#pragma unroll
        for (int i = 0; i < 4; i++) {
            const int kk = kb + i * 4;
            const int ch = kk >> 3;
            const int ho = kk & 4;
            const int c_hi = ((ch    ) ^ s7s) << 3;
            const int c_lo = ((ch + 4) ^ s7s) << 3;
            uint4 va = *(const uint4*)(ag + k0 + i * 4);
            uint4 vb = *(const uint4*)(bg + k0 + i * 4);
            uint2 ha, la, hb, lb;
            ha.x = (va.y & 0xFFFF0000u) | (va.x >> 16);
            ha.y = (va.w & 0xFFFF0000u) | (va.z >> 16);
            la.x = (va.y << 16) | (va.x & 0xFFFFu);
            la.y = (va.w << 16) | (va.z & 0xFFFFu);
            hb.x = (vb.y & 0xFFFF0000u) | (vb.x >> 16);
            hb.y = (vb.w & 0xFFFF0000u) | (vb.z >> 16);
            lb.x = (vb.y << 16) | (vb.x & 0xFFFFu);
            lb.y = (vb.w << 16) | (vb.z & 0xFFFFu);
            *(uint2*)&swA[c_hi + ho] = ha;
            *(uint2*)&swA[c_lo + ho] = la;
            *(uint2*)&swB[c_hi + ho] = hb;
            *(uint2*)&swB[c_lo + ho] = lb;
        }
        __syncthreads();

        short8 Ah[4], Al[4];
#pragma unroll
        for (int mt = 0; mt < 4; mt++) {
            const int row = 64 * wm + 16 * mt + n16;
            const int base = row * 64;
            const int s7 = row & 7;
            Ah[mt] = *(const short8*)&sA[base + (((quad    ) ^ s7) << 3)];
            Al[mt] = *(const short8*)&sA[base + (((quad + 4) ^ s7) << 3)];
        }
#pragma unroll
        for (int nt = 0; nt < 4; nt++) {
            const int row = 64 * wn + 16 * nt + n16;
            const int base = row * 64;
            const int s7 = row & 7;
            short8 Bh = *(const short8*)&sB[base + (((quad    ) ^ s7) << 3)];
            short8 Bl = *(const short8*)&sB[base + (((quad + 4) ^ s7) << 3)];
#pragma unroll
            for (int mt = 0; mt < 4; mt++) {
                acc[mt][nt] = MFMA_BF16(Ah[mt], Bh, acc[mt][nt], 0, 0, 0);
                acc[mt][nt] = MFMA_BF16(Al[mt], Bh, acc[mt][nt], 0, 0, 0);
                acc[mt][nt] = MFMA_BF16(Ah[mt], Bl, acc[mt][nt], 0, 0, 0);
            }
        }
    }

    float bv[4];
#pragma unroll
    for (int nt = 0; nt < 4; nt++)
        bv[nt] = BIAS ? bias[n0 + 64 * wn + 16 * nt + n16] : 0.f;
#pragma unroll
    for (int mt = 0; mt < 4; mt++) {
        const int rbase = m0 + 64 * wm + 16 * mt + 4 * quad;
#pragma unroll
        for (int r = 0; r < 4; r++) {
#pragma unroll
            for (int nt = 0; nt < 4; nt++) {
                const int col = n0 + 64 * wn + 16 * nt + n16;
                Cp[(size_t)(rbase + r) * N + col] = acc[mt][nt][r] + bv[nt];
            }
        }
    }
}

// ---------------------------------------------------------------------------
// Depthwise conv (k=5, pad=2) + sigmoid gate. Writes MSg (f32) + planar
// K-image [bh][n][hi 64 | lo 64] for attention A.
// ---------------------------------------------------------------------------
__global__ __launch_bounds__(128)
void convgate_kernel(const float* __restrict__ qkv1, const float* __restrict__ qkv2,
                     const float* __restrict__ convw,
                     const float* __restrict__ convb,
                     float* __restrict__ MSg, unsigned short* __restrict__ Kimg)
{
    __shared__ float ms[INNER_];
    const int blk = blockIdx.x;
    const int n = blk & (N_ - 1);
    const int b = blk >> 10;
    const int t = threadIdx.x;

    const float4* q1 = (const float4*)(qkv1 + (size_t)blk * QKVC + 3 * INNER_);
    const float4* q2 = (const float4*)(qkv2 + (size_t)blk * QKVC + 3 * INNER_);
    float4 v1 = q1[t], v2 = q2[t];
    float4 s;
    s.x = v1.x + v2.x; s.y = v1.y + v2.y; s.z = v1.z + v2.z; s.w = v1.w + v2.w;
    *(float4*)&ms[t * 4] = s;
    __syncthreads();

    float w[5];
#pragma unroll
    for (int k = 0; k < 5; k++) w[k] = convw[n * 5 + k];
    const float cb = convb[n];

    float out[4];
#pragma unroll
    for (int ff = 0; ff < 4; ff++) {
        int f = t * 4 + ff;
        float A = cb;
#pragma unroll
        for (int k = 0; k < 5; k++) {
            int idx = f + k - 2;
            if (idx >= 0 && idx < INNER_) A += ms[idx] * w[k];
        }
        float sg = 1.f / (1.f + __expf(-A));
        out[ff] = ms[f] * sg;
    }
    *(float4*)&MSg[(size_t)blk * INNER_ + t * 4] = make_float4(out[0], out[1], out[2], out[3]);

    // planar K-image write: head h = t>>4, dims d0..d0+3, token row n
    const int h  = t >> 4;
    const int d0 = (4 * t) & 63;
    unsigned short hs[4], ls[4];
#pragma unroll
    for (int e = 0; e < 4; e++) {
        unsigned int hb = f2b(out[e]);
        float fh = __uint_as_float(hb << 16);
        hs[e] = (unsigned short)hb;
        ls[e] = f2b(out[e] - fh);
    }
    unsigned short* kim = Kimg + ((size_t)(b * 8 + h) * 1024 + n) * 128 + d0;
    uint2 hv; hv.x = (unsigned int)hs[0] | ((unsigned int)hs[1] << 16);
              hv.y = (unsigned int)hs[2] | ((unsigned int)hs[3] << 16);
    uint2 lv; lv.x = (unsigned int)ls[0] | ((unsigned int)ls[1] << 16);
              lv.y = (unsigned int)ls[2] | ((unsigned int)ls[3] << 16);
    *(uint2*)kim        = hv;
    *(uint2*)(kim + 64) = lv;
}

// ---------------------------------------------------------------------------
// MFMA flash attention: 512 threads, Q-tile 128, simple 2-barrier loop.
// K staged via gll from planar image (swizzle in per-lane source offset).
// V reg-staged from f32. Softmax in log2 domain (Q pre-scaled by
// 0.125*log2e) with defer-max. (= R2's attention config + planar K format.)
// ---------------------------------------------------------------------------
template<int NV, bool RESID, bool PACKO, int NPROB>
__global__ __launch_bounds__(512, 2)
void mattn_kernel(const float* __restrict__ Q0, const float* __restrict__ Q1,
                  const unsigned short* __restrict__ K0, const unsigned short* __restrict__ K1,
                  const float* __restrict__ VA0, const float* __restrict__ VA1,
                  const float* __restrict__ VB0, const float* __restrict__ VB1,
                  float* __restrict__ OA0, float* __restrict__ OA1,
                  float* __restrict__ OB0, float* __restrict__ OB1,
                  long long q_sb, long long q_sh, int q_sr,
                  long long k_sb, long long k_sh, int k_rs, int k_po,
                  long long v_sb, long long v_sh, int v_sr,
                  long long o_sb, long long o_sh, int o_sr)
{
    __shared__ __align__(16) unsigned short sK[64 * 128];   // hi|lo planes
    __shared__ __align__(16) unsigned short sV0[64 * 64];   // V^T plain bf16
    __shared__ __align__(16) unsigned short sV1[(NV == 2) ? 64 * 64 : 8];
    __shared__ __align__(16) unsigned short sP[128 * 64];   // P plain bf16

    const int t    = threadIdx.x;
    const int w    = t >> 6;        // wave 0..7
    const int lane = t & 63;
    const int n16  = lane & 15;
    const int quad = lane >> 4;

    // XCD-aware decode
    const int bid = blockIdx.x;
    const int c   = bid & 7;
    const int r1  = bid >> 3;
    const int qt  = r1 & 7;
    const int r2  = r1 >> 3;
    const int g   = r2 & 7;
    const int p   = (NPROB == 2) ? (r2 >> 3) : 0;
    const int bh  = 8 * g + c;
    const int b = bh >> 3, h = bh & 7;
    const int i0 = qt * 128;

    const float* Qb          = (NPROB == 2 && p) ? Q1 : Q0;
    const unsigned short* Kb = (NPROB == 2 && p) ? K1 : K0;
    const float* VAb         = (NPROB == 2 && p) ? VA1 : VA0;
    float* OAb               = (NPROB == 2 && p) ? OA1 : OA0;

    const float* Qg          = Qb + (size_t)b * q_sb + (size_t)h * q_sh;
    const unsigned short* Kg = Kb + (size_t)b * k_sb + (size_t)h * k_sh;
    const float* V0g         = VAb + (size_t)b * v_sb + (size_t)h * v_sh;
    const float* V1g = (NV == 2) ? (VB0 + (size_t)b * v_sb + (size_t)h * v_sh) : nullptr;
    float* O0g = OAb + (size_t)b * o_sb + (size_t)h * o_sh;
    float* O1g = (NV == 2) ? (OB0 + (size_t)b * o_sb + (size_t)h * o_sh) : nullptr;

    // persistent Q fragments (hi/lo split), rows i0+16w+n16,
    // pre-scaled by 0.125 * log2(e) so exps are bare v_exp_f32.
    const float SC2 = 0.1803368801f;
    short8 Qh[2], Ql[2];
#pragma unroll
    for (int s = 0; s < 2; s++) {
        const float* qp = Qg + (size_t)(i0 + 16 * w + n16) * q_sr + 32 * s + 8 * quad;
        float qv[8];
        float4 q0 = *(const float4*)qp;
        float4 q1 = *(const float4*)(qp + 4);
        qv[0]=q0.x*SC2; qv[1]=q0.y*SC2; qv[2]=q0.z*SC2; qv[3]=q0.w*SC2;
        qv[4]=q1.x*SC2; qv[5]=q1.y*SC2; qv[6]=q1.z*SC2; qv[7]=q1.w*SC2;
        split8(qv, Qh[s], Ql[s]);
    }

    float m_ = -1e30f, l_ = 0.f;
    f32x4 O0a[4], O1a[(NV == 2) ? 4 : 1];
#pragma unroll
    for (int nt = 0; nt < 4; nt++) O0a[nt] = (f32x4){0.f,0.f,0.f,0.f};
    if constexpr (NV == 2) {
#pragma unroll
        for (int nt = 0; nt < 4; nt++) O1a[nt] = (f32x4){0.f,0.f,0.f,0.f};
    }

    const int prow = 16 * w + n16;          // 0..127
    const int vc = t & 15, vp = t >> 4;     // V f32 staging: d-chunk, j-pair

    // K staging: lane l of wave w fills sK rows jr=4w+(l>>4) (+32), chunk q=l&15.
    // Planar source: logical chunk lq = q ^ (jr&15) -> plane lq>>3, dchunk lq&7.
    const int jr_l = (w << 2) + (lane >> 4);
    const int lq   = (lane & 15) ^ (jr_l & 15);
    const unsigned short* kg_base = Kg + (size_t)jr_l * k_rs
                                  + (lq >> 3) * k_po + (lq & 7) * 8;
    unsigned short* sKw = &sK[w * 512];

    for (int j0 = 0; j0 < N_; j0 += 64) {
        __syncthreads();

        // ---- stage K: 2x gll16 from planar image
        {
            const unsigned short* kg = kg_base + (size_t)j0 * k_rs;
            gll16(kg, sKw);
            gll16(kg + (size_t)32 * k_rs, sKw + 4096);
        }
        // ---- stage V transposed, plain bf16, j-pair u32 writes
        {
            const int j = 2 * vp;
            const float* a0 = V0g + (size_t)(j0 + j) * v_sr + 4 * vc;
            float4 va = *(const float4*)a0;
            float4 vb = *(const float4*)(a0 + v_sr);
#pragma unroll
            for (int e = 0; e < 4; e++) {
                float fa = (e==0)?va.x:(e==1)?va.y:(e==2)?va.z:va.w;
                float fb = (e==0)?vb.x:(e==1)?vb.y:(e==2)?vb.z:vb.w;
                unsigned int u = (unsigned int)f2b(fa) | ((unsigned int)f2b(fb) << 16);
                const int d = 4 * vc + e;
                const int phys = (vp >> 2) ^ ((d ^ (d >> 2)) & 7);
                *(unsigned int*)&sV0[d * 64 + (phys << 3) + (j & 7)] = u;
            }
            if constexpr (NV == 2) {
                const float* a1 = V1g + (size_t)(j0 + j) * v_sr + 4 * vc;
                float4 wa = *(const float4*)a1;
                float4 wb = *(const float4*)(a1 + v_sr);
#pragma unroll
                for (int e = 0; e < 4; e++) {
                    float fa = (e==0)?wa.x:(e==1)?wa.y:(e==2)?wa.z:wa.w;
                    float fb = (e==0)?wb.x:(e==1)?wb.y:(e==2)?wb.z:wb.w;
                    unsigned int u = (unsigned int)f2b(fa) | ((unsigned int)f2b(fb) << 16);
                    const int d = 4 * vc + e;
                    const int phys = (vp >> 2) ^ ((d ^ (d >> 2)) & 7);
                    *(unsigned int*)&sV1[d * 64 + (phys << 3) + (j & 7)] = u;
                }
            }
        }
        __syncthreads();   // drains gll vmcnt + V lgkm

        // ---- S^T = K.Q^T, split 3-MFMA, frags straight from planes
        f32x4 accS[4];
#pragma unroll
        for (int mt = 0; mt < 4; mt++) accS[mt] = (f32x4){0.f,0.f,0.f,0.f};
#pragma unroll
        for (int s = 0; s < 2; s++) {
#pragma unroll
            for (int mt = 0; mt < 4; mt++) {
                const unsigned short* kb2 = &sK[(16 * mt + n16) * 128];
                short8 kh = *(const short8*)&kb2[(((4*s + quad)    ) ^ n16) << 3];
                short8 kl = *(const short8*)&kb2[(((4*s + quad) + 8) ^ n16) << 3];
                accS[mt] = MFMA_BF16(kl, Qh[s], accS[mt], 0, 0, 0);
                accS[mt] = MFMA_BF16(kh, Ql[s], accS[mt], 0, 0, 0);
                accS[mt] = MFMA_BF16(kh, Qh[s], accS[mt], 0, 0, 0);
            }
        }

        // ---- online softmax (log2 domain), defer-max, wave-local P store
        float tmax = -1e30f;
#pragma unroll
        for (int mt = 0; mt < 4; mt++)
#pragma unroll
            for (int r = 0; r < 4; r++) tmax = fmaxf(tmax, accS[mt][r]);
        tmax = fmaxf(tmax, __shfl_xor(tmax, 16));
        tmax = fmaxf(tmax, __shfl_xor(tmax, 32));
        if (!__all(tmax <= m_ + 11.0f)) {
            const float mnew = fmaxf(m_, tmax);
            const float alpha = __builtin_amdgcn_exp2f(m_ - mnew);
            m_ = mnew;
            l_ *= alpha;
            float ar[4];
#pragma unroll
            for (int r = 0; r < 4; r++) ar[r] = __shfl(alpha, (quad << 2) + r);
#pragma unroll
            for (int nt = 0; nt < 4; nt++) {
#pragma unroll
                for (int r = 0; r < 4; r++) O0a[nt][r] *= ar[r];
                if constexpr (NV == 2)
#pragma unroll
                    for (int r = 0; r < 4; r++) O1a[nt][r] *= ar[r];
            }
        }
        float rsum = 0.f;
#pragma unroll
        for (int mt = 0; mt < 4; mt++) {
            float p0 = __builtin_amdgcn_exp2f(accS[mt][0] - m_);
            float p1 = __builtin_amdgcn_exp2f(accS[mt][1] - m_);
            float p2 = __builtin_amdgcn_exp2f(accS[mt][2] - m_);
            float p3 = __builtin_amdgcn_exp2f(accS[mt][3] - m_);
            rsum += (p0 + p1) + (p2 + p3);
            uint2 u;
            u.x = (unsigned int)f2b(p0) | ((unsigned int)f2b(p1) << 16);
            u.y = (unsigned int)f2b(p2) | ((unsigned int)f2b(p3) << 16);
            const int phys = (2 * mt + (quad >> 1)) ^ (n16 & 7);
            *(uint2*)&sP[prow * 64 + (phys << 3) + 4 * (quad & 1)] = u;
        }
        rsum += __shfl_xor(rsum, 16);
        rsum += __shfl_xor(rsum, 32);
        l_ += rsum;

        // ---- PV: plain bf16, 1 MFMA per fragment
#pragma unroll
        for (int s = 0; s < 2; s++) {
            short8 Pf = *(const short8*)&sP[prow * 64 + (((4*s + quad) ^ (n16 & 7)) << 3)];
#pragma unroll
            for (int nt = 0; nt < 4; nt++) {
                const int d = 16 * nt + n16;
                const int phys = (4*s + quad) ^ ((d ^ (d >> 2)) & 7);
                short8 vf = *(const short8*)&sV0[d * 64 + (phys << 3)];
                O0a[nt] = MFMA_BF16(Pf, vf, O0a[nt], 0, 0, 0);
                if constexpr (NV == 2) {
                    short8 vf1 = *(const short8*)&sV1[d * 64 + (phys << 3)];
                    O1a[nt] = MFMA_BF16(Pf, vf1, O1a[nt], 0, 0, 0);
                }
            }
        }
    }

    // ---- epilogue
    float linv[4];
#pragma unroll
    for (int r = 0; r < 4; r++) linv[r] = 1.0f / __shfl(l_, (quad << 2) + r);
#pragma unroll
    for (int r = 0; r < 4; r++) {
        const int row = i0 + 16 * w + 4 * quad + r;
#pragma unroll
        for (int nt = 0; nt < 4; nt++) {
            const int col = 16 * nt + n16;
            float v = O0a[nt][r] * linv[r];
            if constexpr (RESID) v += V0g[(size_t)row * v_sr + col];
            if constexpr (PACKO)
                ((unsigned int*)O0g)[(size_t)row * o_sr + col] = packsplit(v);
            else
                O0g[(size_t)row * o_sr + col] = v;
            if constexpr (NV == 2) {
                float v1 = O1a[nt][r] * linv[r];
                if constexpr (RESID) v1 += V1g[(size_t)row * v_sr + col];
                if constexpr (PACKO)
                    ((unsigned int*)O1g)[(size_t)row * o_sr + col] = packsplit(v1);
                else
                    O1g[(size_t)row * o_sr + col] = v1;
            }
        }
    }
}

// ---------------------------------------------------------------------------
extern "C" void kernel_launch(void* const* d_in, const int* in_sizes, int n_in,
                              void* d_out, int out_size, void* d_ws, size_t ws_size,
                              hipStream_t stream)
{
    const float* x1    = (const float*)d_in[0];
    const float* x2    = (const float*)d_in[1];
    const float* Wqkv1 = (const float*)d_in[2];
    const float* Wqkv2 = (const float*)d_in[3];
    const float* Wout1 = (const float*)d_in[4];
    const float* bout1 = (const float*)d_in[5];
    const float* Wout2 = (const float*)d_in[6];
    const float* bout2 = (const float*)d_in[7];
    const float* convw = (const float*)d_in[8];
    const float* convb = (const float*)d_in[9];

    const size_t QKV_ELEMS = (size_t)M_ * QKVC;
    const size_t BND_ELEMS = (size_t)M_ * INNER_;
    if (ws_size < (2 * QKV_ELEMS + 5 * BND_ELEMS) * sizeof(float)) return;

    float* ws   = (float*)d_ws;
    float* qkv1 = ws;
    float* qkv2 = qkv1 + QKV_ELEMS;
    float* MSg  = qkv2 + QKV_ELEMS;
    float* u1   = MSg + BND_ELEMS;
    float* u2   = u1 + BND_ELEMS;
    float* t1m  = u2 + BND_ELEMS;
    float* t2m  = t1m + BND_ELEMS;

    // Aliased buffers (time-disjoint):
    unsigned short* x1t   = (unsigned short*)t1m;  // tiled A image, consumed step 1
    unsigned short* x2t   = (unsigned short*)t2m;  // tiled A image, consumed step 1
    unsigned short* KimgA = (unsigned short*)t1m;  // attn-A K-image, step 2 -> 3
    unsigned short* w1t   = (unsigned short*)u2;   // tiled B images, consumed step 1
    unsigned short* w2t   = w1t + (size_t)QKVC * DIM_ * 2;
    unsigned int*   wo1pt = (unsigned int*)u1;     // packed after u1's last read
    unsigned int*   wo2pt = wo1pt + (size_t)DIM_ * DIM_;

    dim3 blk(256);

    // 0) pack activations + qkv weights into pre-swizzled tiled planar images
    pack_a_tiled<<<dim3(M_ * DIM_ / 1024), blk, 0, stream>>>(x1, x1t);
    pack_a_tiled<<<dim3(M_ * DIM_ / 1024), blk, 0, stream>>>(x2, x2t);
    pack_w_tiled<<<dim3(QKVC / 256, DIM_ / 4), blk, 0, stream>>>(Wqkv1, w1t, QKVC);
    pack_w_tiled<<<dim3(QKVC / 256, DIM_ / 4), blk, 0, stream>>>(Wqkv2, w2t, QKVC);

    // 1) QKV projections; k-slice cols [512,1024) written as planar K-image
    gemm_gll<false, true><<<dim3(QKVC / 128, M_ / 128), blk, 0, stream>>>(
        x1t, w1t, nullptr, qkv1, M_, QKVC);
    gemm_gll<false, true><<<dim3(QKVC / 128, M_ / 128), blk, 0, stream>>>(
        x2t, w2t, nullptr, qkv2, M_, QKVC);

    // 2) conv + sigmoid gate -> MSg (f32) + planar K-image for attn A
    convgate_kernel<<<dim3(M_), dim3(128), 0, stream>>>(qkv1, qkv2, convw, convb,
                                                        MSg, KimgA);

    // Stride descriptors
    const long long msg_sb = (long long)N_ * INNER_, msg_sh = HD_;
    const int       msg_sr = INNER_;
    const long long qkv_sb = (long long)N_ * QKVC, qkv_sh = HD_;
    const int       qkv_sr = QKVC;
    const long long u_sb = (long long)H_ * N_ * HD_, u_sh = (long long)N_ * HD_;
    const int       u_sr = HD_;
    // K-image strides (ushort units)
    const long long kA_sb = (long long)8 * N_ * 128, kA_sh = (long long)N_ * 128;
    const long long kB_sb = (long long)N_ * QKVC * 2;

    // 3) Attention A: K = KimgA (planar), Q = MSg, V = qkv v-slices, +resid
    //    outputs u1,u2 as f32 (R2 config)
    mattn_kernel<2, true, false, 1><<<dim3(512), dim3(512), 0, stream>>>(
        MSg, nullptr, KimgA, nullptr,
        qkv1 + 2 * INNER_, nullptr, qkv2 + 2 * INNER_, nullptr,
        u1, nullptr, u2, nullptr,
        msg_sb, msg_sh, msg_sr,
        kA_sb, kA_sh, 128, 64,
        qkv_sb, qkv_sh, qkv_sr,
        u_sb, u_sh, u_sr);

    // 4) Attention B merged pair: K = qkv k-slice planar image, V = u f32,
    //    out packed u32 into t1m/t2m (R2 config)
    mattn_kernel<1, false, true, 2><<<dim3(1024), dim3(512), 0, stream>>>(
        qkv1, qkv2,
        (const unsigned short*)qkv1 + 1024, (const unsigned short*)qkv2 + 1024,
        u1, u2, nullptr, nullptr,
        t1m, t2m, nullptr, nullptr,
        qkv_sb, qkv_sh, qkv_sr,
        kB_sb, 64, QKVC * 2, 512,
        u_sb, u_sh, u_sr,
        msg_sb, msg_sh, msg_sr);

    // 4.5) pack output weights into u1 (u1's last reader was step 4)
    pack_wt<<<dim3(DIM_ / 256, DIM_ / 4), blk, 0, stream>>>(Wout1, wo1pt, DIM_);
    pack_wt<<<dim3(DIM_ / 256, DIM_ / 4), blk, 0, stream>>>(Wout2, wo2pt, DIM_);

    // 5) Output projections (MFMA, bias, f32 out) — reg-staged path
    float* out1 = (float*)d_out;
    float* out2 = out1 + (size_t)M_ * DIM_;
    gemm_mfma<true><<<dim3(DIM_ / 128, M_ / 128), blk, 0, stream>>>(
        (const unsigned int*)t1m, wo1pt, bout1, out1, M_, DIM_);
    gemm_mfma<true><<<dim3(DIM_ / 128, M_ / 128), blk, 0, stream>>>(
        (const unsigned int*)t2m, wo2pt, bout2, out2, M_, DIM_);
}

// Round 9
// 464.413 us; speedup vs baseline: 1.1450x; 1.0030x over previous
//
#include <hip/hip_runtime.h>
#include <hip/hip_bf16.h>

// Problem constants
#define B_     8
#define N_     1024
#define DIM_   512
#define H_     8
#define HD_    64
#define INNER_ 512
#define QKVC   2048   // 4*INNER
#define M_     8192   // B*N

typedef __attribute__((ext_vector_type(8))) short short8;
typedef __attribute__((ext_vector_type(4))) float f32x4;
#define MFMA_BF16 __builtin_amdgcn_mfma_f32_16x16x32_bf16

__device__ __forceinline__ unsigned short f2b(float x) {
    __hip_bfloat16 h = __float2bfloat16(x);
    unsigned short u; __builtin_memcpy(&u, &h, 2); return u;
}
// pack bf16 hi/lo split of x into one u32: (hi<<16)|lo
__device__ __forceinline__ unsigned int packsplit(float x) {
    unsigned int hb = f2b(x);
    float fh = __uint_as_float(hb << 16);
    unsigned int lb = f2b(x - fh);
    return (hb << 16) | lb;
}
__device__ __forceinline__ void split8(const float* v, short8& h, short8& l) {
#pragma unroll
    for (int i = 0; i < 8; i++) {
        unsigned int hb = f2b(v[i]);
        float fh = __uint_as_float(hb << 16);
        h[i] = (short)hb; l[i] = (short)f2b(v[i] - fh);
    }
}
// hi/lo split of two floats -> packed u32s (ushort order: a in low, b in high)
__device__ __forceinline__ void split2x2(float a, float b, unsigned int& h, unsigned int& l) {
    unsigned int ha = f2b(a), hb = f2b(b);
    float fa = __uint_as_float(ha << 16), fb = __uint_as_float(hb << 16);
    h = ha | (hb << 16);
    l = (unsigned int)f2b(a - fa) | ((unsigned int)f2b(b - fb) << 16);
}

// async global->LDS, 16B per lane, LDS dest = wave-uniform base + lane*16
__device__ __forceinline__ void gll16(const unsigned short* g, unsigned short* l) {
    __builtin_amdgcn_global_load_lds(
        (const __attribute__((address_space(1))) void*)g,
        (__attribute__((address_space(3))) void*)l, 16, 0, 0);
}

// ---------------------------------------------------------------------------
// Layout notes
//  K planar image: per token row, [hi-plane D ushorts][lo-plane D ushorts].
//    Consumer (mattn) folds the sK chunk swizzle lq = q ^ (row&15) into the
//    per-lane gll SOURCE offset; the global image itself is linear.
//  V image: per (b,h), 16 blocks of 64 tokens; each block is the EXACT sV
//    LDS image (4096 ushorts): idx = d*64 + (((j>>3) ^ ((d^(d>>2))&7))<<3)
//    + (j&7). Consumer stages with ONE linear gll16 per thread. Producer
//    (attn-A epilogue) writes it with direct 8B register-scatter stores.
// ---------------------------------------------------------------------------

// ---------------------------------------------------------------------------
// Tiled-swizzled planar pack (pre-computed LDS image) for the GEMM.
// Tile (rt, kt) = 16KB = 8192 ushorts at base + (rt*16 + kt)*8192.
// ---------------------------------------------------------------------------
__global__ __launch_bounds__(256)
void pack_a_tiled(const float* __restrict__ in, unsigned short* __restrict__ out)
{
    size_t i = ((size_t)blockIdx.x * 256 + threadIdx.x) * 4;   // element idx, K=512 cols
    float4 v = *(const float4*)(in + i);
    const size_t R = i >> 9;          // row
    const int k  = (int)(i & 511);    // col (multiple of 4)
    const int kt = k >> 5, kk = k & 31;
    const int r  = (int)(R & 127);
    const size_t rt = R >> 7;
    unsigned short* tile = out + (((rt << 4) + kt) << 13) + r * 64;
    unsigned int h01, l01, h23, l23;
    split2x2(v.x, v.y, h01, l01);
    split2x2(v.z, v.w, h23, l23);
    uint2 hv; hv.x = h01; hv.y = h23;
    uint2 lv; lv.x = l01; lv.y = l23;
    const int s7 = r & 7;
    *(uint2*)&tile[(((kk >> 3)     ^ s7) << 3) + (kk & 7)] = hv;
    *(uint2*)&tile[((((kk >> 3)+4) ^ s7) << 3) + (kk & 7)] = lv;
}

// W[k][n] (f32, K=512 rows, N cols) -> B^T tiled-swizzled image (rows = n)
__global__ __launch_bounds__(256)
void pack_w_tiled(const float* __restrict__ W, unsigned short* __restrict__ out, int N)
{
    const int n  = blockIdx.x * 256 + threadIdx.x;
    const int k0 = blockIdx.y * 4;
    float f0 = W[(size_t)(k0 + 0) * N + n];
    float f1 = W[(size_t)(k0 + 1) * N + n];
    float f2 = W[(size_t)(k0 + 2) * N + n];
    float f3 = W[(size_t)(k0 + 3) * N + n];
    const int r  = n & 127;
    const size_t rt = n >> 7;
    const int kt = k0 >> 5, kk = k0 & 31;
    unsigned short* tile = out + (((rt << 4) + kt) << 13) + r * 64;
    unsigned int h01, l01, h23, l23;
    split2x2(f0, f1, h01, l01);
    split2x2(f2, f3, h23, l23);
    uint2 hv; hv.x = h01; hv.y = h23;
    uint2 lv; lv.x = l01; lv.y = l23;
    const int s7 = r & 7;
    *(uint2*)&tile[(((kk >> 3)     ^ s7) << 3) + (kk & 7)] = hv;
    *(uint2*)&tile[((((kk >> 3)+4) ^ s7) << 3) + (kk & 7)] = lv;
}

// Old format pack (kept for out-proj GEMM): W[k][n] -> Wt[n][k] packed u32
__global__ __launch_bounds__(256)
void pack_wt(const float* __restrict__ W, unsigned int* __restrict__ Wt, int N)
{
    const int n = blockIdx.x * 256 + threadIdx.x;
    const int k0 = blockIdx.y * 4;
    uint4 p;
    p.x = packsplit(W[(size_t)(k0 + 0) * N + n]);
    p.y = packsplit(W[(size_t)(k0 + 1) * N + n]);
    p.z = packsplit(W[(size_t)(k0 + 2) * N + n]);
    p.w = packsplit(W[(size_t)(k0 + 3) * N + n]);
    *(uint4*)&Wt[(size_t)n * 512 + k0] = p;
}

// ---------------------------------------------------------------------------
// MFMA split-GEMM, global_load_lds staging from pre-swizzled tiled inputs.
// PACKK: k-slice cols [512,1024) written as PLANAR hi/lo ushorts into the
// dead k region of the qkv row.
// ---------------------------------------------------------------------------
template<bool BIAS, bool PACKK>
__global__ __launch_bounds__(256)
void gemm_gll(const unsigned short* __restrict__ At, const unsigned short* __restrict__ Bt,
              const float* __restrict__ bias, float* __restrict__ Cp,
              int M, int N)
{
    __shared__ __align__(16) unsigned short sA[128 * 64];
    __shared__ __align__(16) unsigned short sB[128 * 64];

    const int t    = threadIdx.x;
    const int lane = t & 63;
    const int w    = t >> 6;
    const int n16  = lane & 15, quad = lane >> 4;
    const int wm   = w >> 1, wn = w & 1;
    const int m0 = blockIdx.y * 128, n0 = blockIdx.x * 128;

    f32x4 acc[4][4];
#pragma unroll
    for (int mt = 0; mt < 4; mt++)
#pragma unroll
        for (int nt = 0; nt < 4; nt++) acc[mt][nt] = (f32x4){0.f, 0.f, 0.f, 0.f};

    const unsigned short* Ag = At + ((size_t)blockIdx.y << 4) * 8192 + (w * 64 + lane) * 8;
    const unsigned short* Bg = Bt + ((size_t)blockIdx.x << 4) * 8192 + (w * 64 + lane) * 8;
    unsigned short* sAw = &sA[w * 512];
    unsigned short* sBw = &sB[w * 512];

    for (int kt = 0; kt < 16; kt++) {
        __syncthreads();
        const size_t ko = (size_t)kt * 8192;
#pragma unroll
        for (int i = 0; i < 4; i++) {
            gll16(Ag + ko + i * 2048, sAw + i * 2048);
            gll16(Bg + ko + i * 2048, sBw + i * 2048);
        }
        __syncthreads();

        short8 Ah[4], Al[4];
#pragma unroll
        for (int mt = 0; mt < 4; mt++) {
            const int row = 64 * wm + 16 * mt + n16;
            const int base = row * 64;
            const int s7 = row & 7;
            Ah[mt] = *(const short8*)&sA[base + (((quad    ) ^ s7) << 3)];
            Al[mt] = *(const short8*)&sA[base + (((quad + 4) ^ s7) << 3)];
        }
#pragma unroll
        for (int nt = 0; nt < 4; nt++) {
            const int row = 64 * wn + 16 * nt + n16;
            const int base = row * 64;
            const int s7 = row & 7;
            short8 Bh = *(const short8*)&sB[base + (((quad    ) ^ s7) << 3)];
            short8 Bl = *(const short8*)&sB[base + (((quad + 4) ^ s7) << 3)];
#pragma unroll
            for (int mt = 0; mt < 4; mt++) {
                acc[mt][nt] = MFMA_BF16(Ah[mt], Bh, acc[mt][nt], 0, 0, 0);
                acc[mt][nt] = MFMA_BF16(Al[mt], Bh, acc[mt][nt], 0, 0, 0);
                acc[mt][nt] = MFMA_BF16(Ah[mt], Bl, acc[mt][nt], 0, 0, 0);
            }
        }
    }

    const bool packout = PACKK && ((n0 >> 9) == 1);   // qkv k-slice cols
    float bv[4];
#pragma unroll
    for (int nt = 0; nt < 4; nt++)
        bv[nt] = BIAS ? bias[n0 + 64 * wn + 16 * nt + n16] : 0.f;
#pragma unroll
    for (int mt = 0; mt < 4; mt++) {
        const int rbase = m0 + 64 * wm + 16 * mt + 4 * quad;
#pragma unroll
        for (int r = 0; r < 4; r++) {
#pragma unroll
            for (int nt = 0; nt < 4; nt++) {
                const int col = n0 + 64 * wn + 16 * nt + n16;
                const int row = rbase + r;
                const float v = acc[mt][nt][r] + bv[nt];
                if (packout) {
                    // planar K-image: hi at [1024+dg], lo at [1536+dg]
                    const int dg = col & 511;
                    unsigned int hb = f2b(v);
                    float fh = __uint_as_float(hb << 16);
                    unsigned short* kim = (unsigned short*)Cp + (size_t)row * (2 * N);
                    kim[1024 + dg] = (unsigned short)hb;
                    kim[1536 + dg] = f2b(v - fh);
                } else {
                    Cp[(size_t)row * N + col] = v;
                }
            }
        }
    }
}

// ---------------------------------------------------------------------------
// OLD register-staged split-GEMM (kept for out-proj: A comes packed u32 from
// the attention epilogue).
// ---------------------------------------------------------------------------
template<bool BIAS>
__global__ __launch_bounds__(256)
void gemm_mfma(const unsigned int* __restrict__ Ap, const unsigned int* __restrict__ Btp,
               const float* __restrict__ bias, float* __restrict__ Cp,
               int M, int N)
{
    const int K = 512;
    __shared__ __align__(16) unsigned short sA[128 * 64];
    __shared__ __align__(16) unsigned short sB[128 * 64];

    const int t    = threadIdx.x;
    const int lane = t & 63;
    const int w    = t >> 6;
    const int n16  = lane & 15, quad = lane >> 4;
    const int wm   = w >> 1, wn = w & 1;
    const int m0 = blockIdx.y * 128, n0 = blockIdx.x * 128;

    f32x4 acc[4][4];
#pragma unroll
    for (int mt = 0; mt < 4; mt++)
#pragma unroll
        for (int nt = 0; nt < 4; nt++) acc[mt][nt] = (f32x4){0.f, 0.f, 0.f, 0.f};

    const int srow = t >> 1;
    const int kb   = (t & 1) * 16;
    const unsigned int* ag = Ap  + (size_t)(m0 + srow) * K + kb;
    const unsigned int* bg = Btp + (size_t)(n0 + srow) * K + kb;
    const int s7s = srow & 7;
    unsigned short* swA = &sA[srow * 64];
    unsigned short* swB = &sB[srow * 64];

    for (int k0 = 0; k0 < K; k0 += 32) {
        __syncthreads();
#pragma unroll
        for (int i = 0; i < 4; i++) {
            const int kk = kb + i * 4;
            const int ch = kk >> 3;
            const int ho = kk & 4;
            const int c_hi = ((ch    ) ^ s7s) << 3;
            const int c_lo = ((ch + 4) ^ s7s) << 3;
            uint4 va = *(const uint4*)(ag + k0 + i * 4);
            uint4 vb = *(const uint4*)(bg + k0 + i * 4);
            uint2 ha, la, hb, lb;
            ha.x = (va.y & 0xFFFF0000u) | (va.x >> 16);
            ha.y = (va.w & 0xFFFF0000u) | (va.z >> 16);
            la.x = (va.y << 16) | (va.x & 0xFFFFu);
            la.y = (va.w << 16) | (va.z & 0xFFFFu);
            hb.x = (vb.y & 0xFFFF0000u) | (vb.x >> 16);
            hb.y = (vb.w & 0xFFFF0000u) | (vb.z >> 16);
            lb.x = (vb.y << 16) | (vb.x & 0xFFFFu);
            lb.y = (vb.w << 16) | (vb.z & 0xFFFFu);
            *(uint2*)&swA[c_hi + ho] = ha;
            *(uint2*)&swA[c_lo + ho] = la;
            *(uint2*)&swB[c_hi + ho] = hb;
            *(uint2*)&swB[c_lo + ho] = lb;
        }
        __syncthreads();

        short8 Ah[4], Al[4];
#pragma unroll
        for (int mt = 0; mt < 4; mt++) {
            const int row = 64 * wm + 16 * mt + n16;
            const int base = row * 64;
            const int s7 = row & 7;
            Ah[mt] = *(const short8*)&sA[base + (((quad    ) ^ s7) << 3)];
            Al[mt] = *(const short8*)&sA[base + (((quad + 4) ^ s7) << 3)];
        }
#pragma unroll
        for (int nt = 0; nt < 4; nt++) {
            const int row = 64 * wn + 16 * nt + n16;
            const int base = row * 64;
            const int s7 = row & 7;
            short8 Bh = *(const short8*)&sB[base + (((quad    ) ^ s7) << 3)];
            short8 Bl = *(const short8*)&sB[base + (((quad + 4) ^ s7) << 3)];
#pragma unroll
            for (int mt = 0; mt < 4; mt++) {
                acc[mt][nt] = MFMA_BF16(Ah[mt], Bh, acc[mt][nt], 0, 0, 0);
                acc[mt][nt] = MFMA_BF16(Al[mt], Bh, acc[mt][nt], 0, 0, 0);
                acc[mt][nt] = MFMA_BF16(Ah[mt], Bl, acc[mt][nt], 0, 0, 0);
            }
        }
    }

    float bv[4];
#pragma unroll
    for (int nt = 0; nt < 4; nt++)
        bv[nt] = BIAS ? bias[n0 + 64 * wn + 16 * nt + n16] : 0.f;
#pragma unroll
    for (int mt = 0; mt < 4; mt++) {
        const int rbase = m0 + 64 * wm + 16 * mt + 4 * quad;
#pragma unroll
        for (int r = 0; r < 4; r++) {
#pragma unroll
            for (int nt = 0; nt < 4; nt++) {
                const int col = n0 + 64 * wn + 16 * nt + n16;
                Cp[(size_t)(rbase + r) * N + col] = acc[mt][nt][r] + bv[nt];
            }
        }
    }
}

// ---------------------------------------------------------------------------
// Depthwise conv (k=5, pad=2) + sigmoid gate. Writes MSg (f32) + planar
// K-image [bh][n][hi 64 | lo 64] for attention A.
// ---------------------------------------------------------------------------
__global__ __launch_bounds__(128)
void convgate_kernel(const float* __restrict__ qkv1, const float* __restrict__ qkv2,
                     const float* __restrict__ convw,
                     const float* __restrict__ convb,
                     float* __restrict__ MSg, unsigned short* __restrict__ Kimg)
{
    __shared__ float ms[INNER_];
    const int blk = blockIdx.x;
    const int n = blk & (N_ - 1);
    const int b = blk >> 10;
    const int t = threadIdx.x;

    const float4* q1 = (const float4*)(qkv1 + (size_t)blk * QKVC + 3 * INNER_);
    const float4* q2 = (const float4*)(qkv2 + (size_t)blk * QKVC + 3 * INNER_);
    float4 v1 = q1[t], v2 = q2[t];
    float4 s;
    s.x = v1.x + v2.x; s.y = v1.y + v2.y; s.z = v1.z + v2.z; s.w = v1.w + v2.w;
    *(float4*)&ms[t * 4] = s;
    __syncthreads();

    float w[5];
#pragma unroll
    for (int k = 0; k < 5; k++) w[k] = convw[n * 5 + k];
    const float cb = convb[n];

    float out[4];
#pragma unroll
    for (int ff = 0; ff < 4; ff++) {
        int f = t * 4 + ff;
        float A = cb;
#pragma unroll
        for (int k = 0; k < 5; k++) {
            int idx = f + k - 2;
            if (idx >= 0 && idx < INNER_) A += ms[idx] * w[k];
        }
        float sg = 1.f / (1.f + __expf(-A));
        out[ff] = ms[f] * sg;
    }
    *(float4*)&MSg[(size_t)blk * INNER_ + t * 4] = make_float4(out[0], out[1], out[2], out[3]);

    // planar K-image write: head h = t>>4, dims d0..d0+3, token row n
    const int h  = t >> 4;
    const int d0 = (4 * t) & 63;
    unsigned short hs[4], ls[4];
#pragma unroll
    for (int e = 0; e < 4; e++) {
        unsigned int hb = f2b(out[e]);
        float fh = __uint_as_float(hb << 16);
        hs[e] = (unsigned short)hb;
        ls[e] = f2b(out[e] - fh);
    }
    unsigned short* kim = Kimg + ((size_t)(b * 8 + h) * 1024 + n) * 128 + d0;
    uint2 hv; hv.x = (unsigned int)hs[0] | ((unsigned int)hs[1] << 16);
              hv.y = (unsigned int)hs[2] | ((unsigned int)hs[3] << 16);
    uint2 lv; lv.x = (unsigned int)ls[0] | ((unsigned int)ls[1] << 16);
              lv.y = (unsigned int)ls[2] | ((unsigned int)ls[3] << 16);
    *(uint2*)kim        = hv;
    *(uint2*)(kim + 64) = lv;
}

// ---------------------------------------------------------------------------
// MFMA flash attention: 512 threads, Q-tile 128, simple 2-barrier loop.
// K staged via gll from planar image (swizzle in per-lane source offset).
// VIMG: V staged via ONE linear gll16 per thread from pre-swizzled V-image.
// IMGO: outputs written as V-images via DIRECT register-scatter 8B stores
// (no LDS transpose, no extra barriers — tests the R3/R5 cost hypothesis).
// Softmax in log2 domain (Q pre-scaled by 0.125*log2e) with defer-max.
// ---------------------------------------------------------------------------
template<int NV, bool RESID, bool PACKO, bool IMGO, bool VIMG, int NPROB>
__global__ __launch_bounds__(512, 2)
void mattn_kernel(const float* __restrict__ Q0, const float* __restrict__ Q1,
                  const unsigned short* __restrict__ K0, const unsigned short* __restrict__ K1,
                  const float* __restrict__ VA0, const float* __restrict__ VA1,
                  const float* __restrict__ VB0, const float* __restrict__ VB1,
                  float* __restrict__ OA0, float* __restrict__ OA1,
                  float* __restrict__ OB0, float* __restrict__ OB1,
                  long long q_sb, long long q_sh, int q_sr,
                  long long k_sb, long long k_sh, int k_rs, int k_po,
                  long long v_sb, long long v_sh, int v_sr,
                  long long o_sb, long long o_sh, int o_sr)
{
    __shared__ __align__(16) unsigned short sK[64 * 128];   // hi|lo planes
    __shared__ __align__(16) unsigned short sV0[64 * 64];   // V^T plain bf16
    __shared__ __align__(16) unsigned short sV1[(NV == 2) ? 64 * 64 : 8];
    __shared__ __align__(16) unsigned short sP[128 * 64];   // P plain bf16

    const int t    = threadIdx.x;
    const int w    = t >> 6;        // wave 0..7
    const int lane = t & 63;
    const int n16  = lane & 15;
    const int quad = lane >> 4;

    // XCD-aware decode
    const int bid = blockIdx.x;
    const int c   = bid & 7;
    const int r1  = bid >> 3;
    const int qt  = r1 & 7;
    const int r2  = r1 >> 3;
    const int g   = r2 & 7;
    const int p   = (NPROB == 2) ? (r2 >> 3) : 0;
    const int bh  = 8 * g + c;
    const int b = bh >> 3, h = bh & 7;
    const int i0 = qt * 128;

    const float* Qb          = (NPROB == 2 && p) ? Q1 : Q0;
    const unsigned short* Kb = (NPROB == 2 && p) ? K1 : K0;
    const float* VAb         = (NPROB == 2 && p) ? VA1 : VA0;
    float* OAb               = (NPROB == 2 && p) ? OA1 : OA0;

    const float* Qg          = Qb + (size_t)b * q_sb + (size_t)h * q_sh;
    const unsigned short* Kg = Kb + (size_t)b * k_sb + (size_t)h * k_sh;

    const float* V0g = nullptr;
    const float* V1g = nullptr;
    const unsigned short* Vus = nullptr;
    if constexpr (VIMG) {
        Vus = (const unsigned short*)VAb + (size_t)b * v_sb + (size_t)h * v_sh;
    } else {
        V0g = VAb + (size_t)b * v_sb + (size_t)h * v_sh;
        if constexpr (NV == 2)
            V1g = VB0 + (size_t)b * v_sb + (size_t)h * v_sh;
    }

    float* O0g = nullptr; float* O1g = nullptr;
    unsigned short* img0 = nullptr; unsigned short* img1 = nullptr;
    if constexpr (IMGO) {
        img0 = (unsigned short*)OAb + (size_t)b * o_sb + (size_t)h * o_sh;
        if constexpr (NV == 2)
            img1 = (unsigned short*)OB0 + (size_t)b * o_sb + (size_t)h * o_sh;
    } else {
        O0g = OAb + (size_t)b * o_sb + (size_t)h * o_sh;
        if constexpr (NV == 2)
            O1g = OB0 + (size_t)b * o_sb + (size_t)h * o_sh;
    }

    // persistent Q fragments (hi/lo split), rows i0+16w+n16,
    // pre-scaled by 0.125 * log2(e) so exps are bare v_exp_f32.
    const float SC2 = 0.1803368801f;
    short8 Qh[2], Ql[2];
#pragma unroll
    for (int s = 0; s < 2; s++) {
        const float* qp = Qg + (size_t)(i0 + 16 * w + n16) * q_sr + 32 * s + 8 * quad;
        float qv[8];
        float4 q0 = *(const float4*)qp;
        float4 q1 = *(const float4*)(qp + 4);
        qv[0]=q0.x*SC2; qv[1]=q0.y*SC2; qv[2]=q0.z*SC2; qv[3]=q0.w*SC2;
        qv[4]=q1.x*SC2; qv[5]=q1.y*SC2; qv[6]=q1.z*SC2; qv[7]=q1.w*SC2;
        split8(qv, Qh[s], Ql[s]);
    }

    float m_ = -1e30f, l_ = 0.f;
    f32x4 O0a[4], O1a[(NV == 2) ? 4 : 1];
#pragma unroll
    for (int nt = 0; nt < 4; nt++) O0a[nt] = (f32x4){0.f,0.f,0.f,0.f};
    if constexpr (NV == 2) {
#pragma unroll
        for (int nt = 0; nt < 4; nt++) O1a[nt] = (f32x4){0.f,0.f,0.f,0.f};
    }

    const int prow = 16 * w + n16;          // 0..127
    const int vc = t & 15, vp = t >> 4;     // V f32 staging: d-chunk, j-pair

    // K staging: lane l of wave w fills sK rows jr=4w+(l>>4) (+32), chunk q=l&15.
    // Planar source: logical chunk lq = q ^ (jr&15) -> plane lq>>3, dchunk lq&7.
    const int jr_l = (w << 2) + (lane >> 4);
    const int lq   = (lane & 15) ^ (jr_l & 15);
    const unsigned short* kg_base = Kg + (size_t)jr_l * k_rs
                                  + (lq >> 3) * k_po + (lq & 7) * 8;
    unsigned short* sKw = &sK[w * 512];

    for (int j0 = 0; j0 < N_; j0 += 64) {
        __syncthreads();

        // ---- stage K: 2x gll16 from planar image
        {
            const unsigned short* kg = kg_base + (size_t)j0 * k_rs;
            gll16(kg, sKw);
            gll16(kg + (size_t)32 * k_rs, sKw + 4096);
        }
        // ---- stage V
        if constexpr (VIMG) {
            gll16(Vus + (size_t)(j0 >> 6) * 4096 + t * 8, &sV0[w * 512]);
        } else {
            const int j = 2 * vp;
            const float* a0 = V0g + (size_t)(j0 + j) * v_sr + 4 * vc;
            float4 va = *(const float4*)a0;
            float4 vb = *(const float4*)(a0 + v_sr);
#pragma unroll
            for (int e = 0; e < 4; e++) {
                float fa = (e==0)?va.x:(e==1)?va.y:(e==2)?va.z:va.w;
                float fb = (e==0)?vb.x:(e==1)?vb.y:(e==2)?vb.z:vb.w;
                unsigned int u = (unsigned int)f2b(fa) | ((unsigned int)f2b(fb) << 16);
                const int d = 4 * vc + e;
                const int phys = (vp >> 2) ^ ((d ^ (d >> 2)) & 7);
                *(unsigned int*)&sV0[d * 64 + (phys << 3) + (j & 7)] = u;
            }
            if constexpr (NV == 2) {
                const float* a1 = V1g + (size_t)(j0 + j) * v_sr + 4 * vc;
                float4 wa = *(const float4*)a1;
                float4 wb = *(const float4*)(a1 + v_sr);
#pragma unroll
                for (int e = 0; e < 4; e++) {
                    float fa = (e==0)?wa.x:(e==1)?wa.y:(e==2)?wa.z:wa.w;
                    float fb = (e==0)?wb.x:(e==1)?wb.y:(e==2)?wb.z:wb.w;
                    unsigned int u = (unsigned int)f2b(fa) | ((unsigned int)f2b(fb) << 16);
                    const int d = 4 * vc + e;
                    const int phys = (vp >> 2) ^ ((d ^ (d >> 2)) & 7);
                    *(unsigned int*)&sV1[d * 64 + (phys << 3) + (j & 7)] = u;
                }
            }
        }
        __syncthreads();   // drains gll vmcnt + V lgkm

        // ---- S^T = K.Q^T, split 3-MFMA, frags straight from planes
        f32x4 accS[4];
#pragma unroll
        for (int mt = 0; mt < 4; mt++) accS[mt] = (f32x4){0.f,0.f,0.f,0.f};
#pragma unroll
        for (int s = 0; s < 2; s++) {
#pragma unroll
            for (int mt = 0; mt < 4; mt++) {
                const unsigned short* kb2 = &sK[(16 * mt + n16) * 128];
                short8 kh = *(const short8*)&kb2[(((4*s + quad)    ) ^ n16) << 3];
                short8 kl = *(const short8*)&kb2[(((4*s + quad) + 8) ^ n16) << 3];
                accS[mt] = MFMA_BF16(kl, Qh[s], accS[mt], 0, 0, 0);
                accS[mt] = MFMA_BF16(kh, Ql[s], accS[mt], 0, 0, 0);
                accS[mt] = MFMA_BF16(kh, Qh[s], accS[mt], 0, 0, 0);
            }
        }

        // ---- online softmax (log2 domain), defer-max, wave-local P store
        float tmax = -1e30f;
#pragma unroll
        for (int mt = 0; mt < 4; mt++)
#pragma unroll
            for (int r = 0; r < 4; r++) tmax = fmaxf(tmax, accS[mt][r]);
        tmax = fmaxf(tmax, __shfl_xor(tmax, 16));
        tmax = fmaxf(tmax, __shfl_xor(tmax, 32));
        if (!__all(tmax <= m_ + 11.0f)) {
            const float mnew = fmaxf(m_, tmax);
            const float alpha = __builtin_amdgcn_exp2f(m_ - mnew);
            m_ = mnew;
            l_ *= alpha;
            float ar[4];
#pragma unroll
            for (int r = 0; r < 4; r++) ar[r] = __shfl(alpha, (quad << 2) + r);
#pragma unroll
            for (int nt = 0; nt < 4; nt++) {
#pragma unroll
                for (int r = 0; r < 4; r++) O0a[nt][r] *= ar[r];
                if constexpr (NV == 2)
#pragma unroll
                    for (int r = 0; r < 4; r++) O1a[nt][r] *= ar[r];
            }
        }
        float rsum = 0.f;
#pragma unroll
        for (int mt = 0; mt < 4; mt++) {
            float p0 = __builtin_amdgcn_exp2f(accS[mt][0] - m_);
            float p1 = __builtin_amdgcn_exp2f(accS[mt][1] - m_);
            float p2 = __builtin_amdgcn_exp2f(accS[mt][2] - m_);
            float p3 = __builtin_amdgcn_exp2f(accS[mt][3] - m_);
            rsum += (p0 + p1) + (p2 + p3);
            uint2 u;
            u.x = (unsigned int)f2b(p0) | ((unsigned int)f2b(p1) << 16);
            u.y = (unsigned int)f2b(p2) | ((unsigned int)f2b(p3) << 16);
            const int phys = (2 * mt + (quad >> 1)) ^ (n16 & 7);
            *(uint2*)&sP[prow * 64 + (phys << 3) + 4 * (quad & 1)] = u;
        }
        rsum += __shfl_xor(rsum, 16);
        rsum += __shfl_xor(rsum, 32);
        l_ += rsum;

        // ---- PV: plain bf16, 1 MFMA per fragment
#pragma unroll
        for (int s = 0; s < 2; s++) {
            short8 Pf = *(const short8*)&sP[prow * 64 + (((4*s + quad) ^ (n16 & 7)) << 3)];
#pragma unroll
            for (int nt = 0; nt < 4; nt++) {
                const int d = 16 * nt + n16;
                const int phys = (4*s + quad) ^ ((d ^ (d >> 2)) & 7);
                short8 vf = *(const short8*)&sV0[d * 64 + (phys << 3)];
                O0a[nt] = MFMA_BF16(Pf, vf, O0a[nt], 0, 0, 0);
                if constexpr (NV == 2) {
                    short8 vf1 = *(const short8*)&sV1[d * 64 + (phys << 3)];
                    O1a[nt] = MFMA_BF16(Pf, vf1, O1a[nt], 0, 0, 0);
                }
            }
        }
    }

    // ---- epilogue
    float linv[4];
#pragma unroll
    for (int r = 0; r < 4; r++) linv[r] = 1.0f / __shfl(l_, (quad << 2) + r);

    if constexpr (IMGO) {
        // Direct register-scatter V-image write: for each d, the 4 r-values
        // land at consecutive j7 slots of one (blk, d, jg) group -> 8B store.
        const int blk = 2 * qt + (w >> 2);
        const int jg  = (2 * w + (quad >> 1)) & 7;
        const int j7b = 4 * (quad & 1);
#pragma unroll
        for (int nt = 0; nt < 4; nt++) {
            const int d = 16 * nt + n16;
            const int swd = (d ^ (d >> 2)) & 7;
            const size_t off = (size_t)blk * 4096 + d * 64 + ((jg ^ swd) << 3) + j7b;
            unsigned short o0[4], o1[4];
#pragma unroll
            for (int r = 0; r < 4; r++) {
                const int row = i0 + 16 * w + 4 * quad + r;
                float v = O0a[nt][r] * linv[r];
                if constexpr (RESID) v += V0g[(size_t)row * v_sr + d];
                o0[r] = f2b(v);
                if constexpr (NV == 2) {
                    float v1 = O1a[nt][r] * linv[r];
                    if constexpr (RESID) v1 += V1g[(size_t)row * v_sr + d];
                    o1[r] = f2b(v1);
                }
            }
            uint2 u0;
            u0.x = (unsigned int)o0[0] | ((unsigned int)o0[1] << 16);
            u0.y = (unsigned int)o0[2] | ((unsigned int)o0[3] << 16);
            *(uint2*)&img0[off] = u0;
            if constexpr (NV == 2) {
                uint2 u1v;
                u1v.x = (unsigned int)o1[0] | ((unsigned int)o1[1] << 16);
                u1v.y = (unsigned int)o1[2] | ((unsigned int)o1[3] << 16);
                *(uint2*)&img1[off] = u1v;
            }
        }
    } else {
#pragma unroll
        for (int r = 0; r < 4; r++) {
            const int row = i0 + 16 * w + 4 * quad + r;
#pragma unroll
            for (int nt = 0; nt < 4; nt++) {
                const int col = 16 * nt + n16;
                float v = O0a[nt][r] * linv[r];
                if constexpr (RESID) v += V0g[(size_t)row * v_sr + col];
                if constexpr (PACKO)
                    ((unsigned int*)O0g)[(size_t)row * o_sr + col] = packsplit(v);
                else
                    O0g[(size_t)row * o_sr + col] = v;
                if constexpr (NV == 2) {
                    float v1 = O1a[nt][r] * linv[r];
                    if constexpr (RESID) v1 += V1g[(size_t)row * v_sr + col];
                    if constexpr (PACKO)
                        ((unsigned int*)O1g)[(size_t)row * o_sr + col] = packsplit(v1);
                    else
                        O1g[(size_t)row * o_sr + col] = v1;
                }
            }
        }
    }
}

// ---------------------------------------------------------------------------
extern "C" void kernel_launch(void* const* d_in, const int* in_sizes, int n_in,
                              void* d_out, int out_size, void* d_ws, size_t ws_size,
                              hipStream_t stream)
{
    const float* x1    = (const float*)d_in[0];
    const float* x2    = (const float*)d_in[1];
    const float* Wqkv1 = (const float*)d_in[2];
    const float* Wqkv2 = (const float*)d_in[3];
    const float* Wout1 = (const float*)d_in[4];
    const float* bout1 = (const float*)d_in[5];
    const float* Wout2 = (const float*)d_in[6];
    const float* bout2 = (const float*)d_in[7];
    const float* convw = (const float*)d_in[8];
    const float* convb = (const float*)d_in[9];

    const size_t QKV_ELEMS = (size_t)M_ * QKVC;
    const size_t BND_ELEMS = (size_t)M_ * INNER_;
    if (ws_size < (2 * QKV_ELEMS + 5 * BND_ELEMS) * sizeof(float)) return;

    float* ws   = (float*)d_ws;
    float* qkv1 = ws;
    float* qkv2 = qkv1 + QKV_ELEMS;
    float* MSg  = qkv2 + QKV_ELEMS;
    float* u1   = MSg + BND_ELEMS;
    float* u2   = u1 + BND_ELEMS;
    float* t1m  = u2 + BND_ELEMS;
    float* t2m  = t1m + BND_ELEMS;

    // Aliased buffers (time-disjoint):
    unsigned short* x1t   = (unsigned short*)t1m;  // tiled A image, consumed step 1
    unsigned short* x2t   = (unsigned short*)t2m;  // tiled A image, consumed step 1
    unsigned short* KimgA = (unsigned short*)t1m;  // attn-A K-image, step 2 -> 3
    unsigned short* w1t   = (unsigned short*)u2;   // tiled B images, consumed step 1
    unsigned short* w2t   = w1t + (size_t)QKVC * DIM_ * 2;
    unsigned short* u1img = (unsigned short*)u1;   // u V-image, step 3 -> 4
    unsigned short* u2img = (unsigned short*)u2;
    unsigned int*   wo1pt = (unsigned int*)u1;     // packed after u1's last read
    unsigned int*   wo2pt = wo1pt + (size_t)DIM_ * DIM_;

    dim3 blk(256);

    // 0) pack activations + qkv weights into pre-swizzled tiled planar images
    pack_a_tiled<<<dim3(M_ * DIM_ / 1024), blk, 0, stream>>>(x1, x1t);
    pack_a_tiled<<<dim3(M_ * DIM_ / 1024), blk, 0, stream>>>(x2, x2t);
    pack_w_tiled<<<dim3(QKVC / 256, DIM_ / 4), blk, 0, stream>>>(Wqkv1, w1t, QKVC);
    pack_w_tiled<<<dim3(QKVC / 256, DIM_ / 4), blk, 0, stream>>>(Wqkv2, w2t, QKVC);

    // 1) QKV projections; k-slice cols [512,1024) written as planar K-image
    gemm_gll<false, true><<<dim3(QKVC / 128, M_ / 128), blk, 0, stream>>>(
        x1t, w1t, nullptr, qkv1, M_, QKVC);
    gemm_gll<false, true><<<dim3(QKVC / 128, M_ / 128), blk, 0, stream>>>(
        x2t, w2t, nullptr, qkv2, M_, QKVC);

    // 2) conv + sigmoid gate -> MSg (f32) + planar K-image for attn A
    convgate_kernel<<<dim3(M_), dim3(128), 0, stream>>>(qkv1, qkv2, convw, convb,
                                                        MSg, KimgA);

    // Stride descriptors
    const long long msg_sb = (long long)N_ * INNER_, msg_sh = HD_;
    const int       msg_sr = INNER_;
    const long long qkv_sb = (long long)N_ * QKVC, qkv_sh = HD_;
    const int       qkv_sr = QKVC;
    // K-image strides (ushort units)
    const long long kA_sb = (long long)8 * N_ * 128, kA_sh = (long long)N_ * 128;
    const long long kB_sb = (long long)N_ * QKVC * 2;
    // u V-image strides (ushort units)
    const long long ui_sb = (long long)H_ * N_ * HD_, ui_sh = (long long)N_ * HD_;

    // 3) Attention A: K = KimgA (planar), Q = MSg, V = qkv v-slices (f32),
    //    +resid; outputs u1,u2 as V-images via direct register-scatter
    mattn_kernel<2, true, false, true, false, 1><<<dim3(512), dim3(512), 0, stream>>>(
        MSg, nullptr, KimgA, nullptr,
        qkv1 + 2 * INNER_, nullptr, qkv2 + 2 * INNER_, nullptr,
        (float*)u1img, nullptr, (float*)u2img, nullptr,
        msg_sb, msg_sh, msg_sr,
        kA_sb, kA_sh, 128, 64,
        qkv_sb, qkv_sh, qkv_sr,
        ui_sb, ui_sh, HD_);

    // 4) Attention B merged pair: K = qkv k-slice planar image, V = u images
    //    (one linear gll16 per tile), out packed u32 into t1m/t2m
    mattn_kernel<1, false, true, false, true, 2><<<dim3(1024), dim3(512), 0, stream>>>(
        qkv1, qkv2,
        (const unsigned short*)qkv1 + 1024, (const unsigned short*)qkv2 + 1024,
        (const float*)u1img, (const float*)u2img, nullptr, nullptr,
        t1m, t2m, nullptr, nullptr,
        qkv_sb, qkv_sh, qkv_sr,
        kB_sb, 64, QKVC * 2, 512,
        ui_sb, ui_sh, HD_,
        msg_sb, msg_sh, msg_sr);

    // 4.5) pack output weights into u1 (u1's last reader was step 4)
    pack_wt<<<dim3(DIM_ / 256, DIM_ / 4), blk, 0, stream>>>(Wout1, wo1pt, DIM_);
    pack_wt<<<dim3(DIM_ / 256, DIM_ / 4), blk, 0, stream>>>(Wout2, wo2pt, DIM_);

    // 5) Output projections (MFMA, bias, f32 out) — reg-staged path
    float* out1 = (float*)d_out;
    float* out2 = out1 + (size_t)M_ * DIM_;
    gemm_mfma<true><<<dim3(DIM_ / 128, M_ / 128), blk, 0, stream>>>(
        (const unsigned int*)t1m, wo1pt, bout1, out1, M_, DIM_);
    gemm_mfma<true><<<dim3(DIM_ / 128, M_ / 128), blk, 0, stream>>>(
        (const unsigned int*)t2m, wo2pt, bout2, out2, M_, DIM_);
}

// Round 10
// 413.093 us; speedup vs baseline: 1.2872x; 1.1242x over previous
//
#include <hip/hip_runtime.h>
#include <hip/hip_bf16.h>

// Problem constants
#define B_     8
#define N_     1024
#define DIM_   512
#define H_     8
#define HD_    64
#define INNER_ 512
#define QKVC   2048   // 4*INNER
#define M_     8192   // B*N

typedef __attribute__((ext_vector_type(8))) short short8;
typedef __attribute__((ext_vector_type(4))) float f32x4;
#define MFMA_BF16 __builtin_amdgcn_mfma_f32_16x16x32_bf16

__device__ __forceinline__ unsigned short f2b(float x) {
    __hip_bfloat16 h = __float2bfloat16(x);
    unsigned short u; __builtin_memcpy(&u, &h, 2); return u;
}
__device__ __forceinline__ void split8(const float* v, short8& h, short8& l) {
#pragma unroll
    for (int i = 0; i < 8; i++) {
        unsigned int hb = f2b(v[i]);
        float fh = __uint_as_float(hb << 16);
        h[i] = (short)hb; l[i] = (short)f2b(v[i] - fh);
    }
}
// hi/lo split of two floats -> packed u32s (ushort order: a in low, b in high)
__device__ __forceinline__ void split2x2(float a, float b, unsigned int& h, unsigned int& l) {
    unsigned int ha = f2b(a), hb = f2b(b);
    float fa = __uint_as_float(ha << 16), fb = __uint_as_float(hb << 16);
    h = ha | (hb << 16);
    l = (unsigned int)f2b(a - fa) | ((unsigned int)f2b(b - fb) << 16);
}

// async global->LDS, 16B per lane, LDS dest = wave-uniform base + lane*16
__device__ __forceinline__ void gll16(const unsigned short* g, unsigned short* l) {
    __builtin_amdgcn_global_load_lds(
        (const __attribute__((address_space(1))) void*)g,
        (__attribute__((address_space(3))) void*)l, 16, 0, 0);
}

// ---------------------------------------------------------------------------
// Layout notes
//  GEMM A/B image: tile (rt,kt) = 8192 ushorts at ((rt*16+kt)<<13); within,
//    row r = 64 ushorts; hi of kk at (((kk>>3)^(r&7))<<3)+(kk&7), lo at
//    ((((kk>>3)+4)^(r&7))<<3)+(kk&7). Producers: pack_a_tiled, pack_w_tiled,
//    attn-B IMGA epilogue (2B register scatter — measured free, R8).
//  K planar image: per token row, [hi-plane 64 ushorts][lo-plane 64 ushorts];
//    consumer folds chunk swizzle into per-lane gll source offset.
//  V image: per (b,h), 16 blocks of 64 tokens; block = EXACT sV LDS image:
//    idx = d*64 + (((j>>3) ^ ((d^(d>>2))&7))<<3) + (j&7).
// ---------------------------------------------------------------------------

__global__ __launch_bounds__(256)
void pack_a_tiled(const float* __restrict__ in, unsigned short* __restrict__ out)
{
    size_t i = ((size_t)blockIdx.x * 256 + threadIdx.x) * 4;   // element idx, K=512 cols
    float4 v = *(const float4*)(in + i);
    const size_t R = i >> 9;          // row
    const int k  = (int)(i & 511);    // col (multiple of 4)
    const int kt = k >> 5, kk = k & 31;
    const int r  = (int)(R & 127);
    const size_t rt = R >> 7;
    unsigned short* tile = out + (((rt << 4) + kt) << 13) + r * 64;
    unsigned int h01, l01, h23, l23;
    split2x2(v.x, v.y, h01, l01);
    split2x2(v.z, v.w, h23, l23);
    uint2 hv; hv.x = h01; hv.y = h23;
    uint2 lv; lv.x = l01; lv.y = l23;
    const int s7 = r & 7;
    *(uint2*)&tile[(((kk >> 3)     ^ s7) << 3) + (kk & 7)] = hv;
    *(uint2*)&tile[((((kk >> 3)+4) ^ s7) << 3) + (kk & 7)] = lv;
}

// W[k][n] (f32, K=512 rows, N cols) -> B^T tiled-swizzled image (rows = n)
__global__ __launch_bounds__(256)
void pack_w_tiled(const float* __restrict__ W, unsigned short* __restrict__ out, int N)
{
    const int n  = blockIdx.x * 256 + threadIdx.x;
    const int k0 = blockIdx.y * 4;
    float f0 = W[(size_t)(k0 + 0) * N + n];
    float f1 = W[(size_t)(k0 + 1) * N + n];
    float f2 = W[(size_t)(k0 + 2) * N + n];
    float f3 = W[(size_t)(k0 + 3) * N + n];
    const int r  = n & 127;
    const size_t rt = n >> 7;
    const int kt = k0 >> 5, kk = k0 & 31;
    unsigned short* tile = out + (((rt << 4) + kt) << 13) + r * 64;
    unsigned int h01, l01, h23, l23;
    split2x2(f0, f1, h01, l01);
    split2x2(f2, f3, h23, l23);
    uint2 hv; hv.x = h01; hv.y = h23;
    uint2 lv; lv.x = l01; lv.y = l23;
    const int s7 = r & 7;
    *(uint2*)&tile[(((kk >> 3)     ^ s7) << 3) + (kk & 7)] = hv;
    *(uint2*)&tile[((((kk >> 3)+4) ^ s7) << 3) + (kk & 7)] = lv;
}

// ---------------------------------------------------------------------------
// MFMA split-GEMM, global_load_lds staging from pre-swizzled tiled inputs.
// NPROB=2: blockIdx.z selects problem (merged dispatch, deeper block queue).
// PACKK: k-slice cols [512,1024) written as planar K-image into dead qkv k.
// ---------------------------------------------------------------------------
template<bool BIAS, bool PACKK, int NPROB>
__global__ __launch_bounds__(256)
void gemm_gll(const unsigned short* __restrict__ At0, const unsigned short* __restrict__ At1,
              const unsigned short* __restrict__ Bt0, const unsigned short* __restrict__ Bt1,
              const float* __restrict__ bias0, const float* __restrict__ bias1,
              float* __restrict__ Cp0, float* __restrict__ Cp1,
              int M, int N)
{
    __shared__ __align__(16) unsigned short sA[128 * 64];
    __shared__ __align__(16) unsigned short sB[128 * 64];

    const int z = (NPROB == 2) ? blockIdx.z : 0;
    const unsigned short* At = z ? At1 : At0;
    const unsigned short* Bt = z ? Bt1 : Bt0;
    const float* bias        = z ? bias1 : bias0;
    float* Cp                = z ? Cp1 : Cp0;

    const int t    = threadIdx.x;
    const int lane = t & 63;
    const int w    = t >> 6;
    const int n16  = lane & 15, quad = lane >> 4;
    const int wm   = w >> 1, wn = w & 1;
    const int m0 = blockIdx.y * 128, n0 = blockIdx.x * 128;

    f32x4 acc[4][4];
#pragma unroll
    for (int mt = 0; mt < 4; mt++)
#pragma unroll
        for (int nt = 0; nt < 4; nt++) acc[mt][nt] = (f32x4){0.f, 0.f, 0.f, 0.f};

    const unsigned short* Ag = At + ((size_t)blockIdx.y << 4) * 8192 + (w * 64 + lane) * 8;
    const unsigned short* Bg = Bt + ((size_t)blockIdx.x << 4) * 8192 + (w * 64 + lane) * 8;
    unsigned short* sAw = &sA[w * 512];
    unsigned short* sBw = &sB[w * 512];

    for (int kt = 0; kt < 16; kt++) {
        __syncthreads();
        const size_t ko = (size_t)kt * 8192;
#pragma unroll
        for (int i = 0; i < 4; i++) {
            gll16(Ag + ko + i * 2048, sAw + i * 2048);
            gll16(Bg + ko + i * 2048, sBw + i * 2048);
        }
        __syncthreads();

        short8 Ah[4], Al[4];
#pragma unroll
        for (int mt = 0; mt < 4; mt++) {
            const int row = 64 * wm + 16 * mt + n16;
            const int base = row * 64;
            const int s7 = row & 7;
            Ah[mt] = *(const short8*)&sA[base + (((quad    ) ^ s7) << 3)];
            Al[mt] = *(const short8*)&sA[base + (((quad + 4) ^ s7) << 3)];
        }
#pragma unroll
        for (int nt = 0; nt < 4; nt++) {
            const int row = 64 * wn + 16 * nt + n16;
            const int base = row * 64;
            const int s7 = row & 7;
            short8 Bh = *(const short8*)&sB[base + (((quad    ) ^ s7) << 3)];
            short8 Bl = *(const short8*)&sB[base + (((quad + 4) ^ s7) << 3)];
#pragma unroll
            for (int mt = 0; mt < 4; mt++) {
                acc[mt][nt] = MFMA_BF16(Ah[mt], Bh, acc[mt][nt], 0, 0, 0);
                acc[mt][nt] = MFMA_BF16(Al[mt], Bh, acc[mt][nt], 0, 0, 0);
                acc[mt][nt] = MFMA_BF16(Ah[mt], Bl, acc[mt][nt], 0, 0, 0);
            }
        }
    }

    const bool packout = PACKK && ((n0 >> 9) == 1);   // qkv k-slice cols
    float bv[4];
#pragma unroll
    for (int nt = 0; nt < 4; nt++)
        bv[nt] = BIAS ? bias[n0 + 64 * wn + 16 * nt + n16] : 0.f;
#pragma unroll
    for (int mt = 0; mt < 4; mt++) {
        const int rbase = m0 + 64 * wm + 16 * mt + 4 * quad;
#pragma unroll
        for (int r = 0; r < 4; r++) {
#pragma unroll
            for (int nt = 0; nt < 4; nt++) {
                const int col = n0 + 64 * wn + 16 * nt + n16;
                const int row = rbase + r;
                const float v = acc[mt][nt][r] + bv[nt];
                if (packout) {
                    // planar K-image: hi at [1024+dg], lo at [1536+dg]
                    const int dg = col & 511;
                    unsigned int hb = f2b(v);
                    float fh = __uint_as_float(hb << 16);
                    unsigned short* kim = (unsigned short*)Cp + (size_t)row * (2 * N);
                    kim[1024 + dg] = (unsigned short)hb;
                    kim[1536 + dg] = f2b(v - fh);
                } else {
                    Cp[(size_t)row * N + col] = v;
                }
            }
        }
    }
}

// ---------------------------------------------------------------------------
// Depthwise conv (k=5, pad=2) + sigmoid gate. Writes MSg (f32) + planar
// K-image [bh][n][hi 64 | lo 64] for attention A.
// ---------------------------------------------------------------------------
__global__ __launch_bounds__(128)
void convgate_kernel(const float* __restrict__ qkv1, const float* __restrict__ qkv2,
                     const float* __restrict__ convw,
                     const float* __restrict__ convb,
                     float* __restrict__ MSg, unsigned short* __restrict__ Kimg)
{
    __shared__ float ms[INNER_];
    const int blk = blockIdx.x;
    const int n = blk & (N_ - 1);
    const int b = blk >> 10;
    const int t = threadIdx.x;

    const float4* q1 = (const float4*)(qkv1 + (size_t)blk * QKVC + 3 * INNER_);
    const float4* q2 = (const float4*)(qkv2 + (size_t)blk * QKVC + 3 * INNER_);
    float4 v1 = q1[t], v2 = q2[t];
    float4 s;
    s.x = v1.x + v2.x; s.y = v1.y + v2.y; s.z = v1.z + v2.z; s.w = v1.w + v2.w;
    *(float4*)&ms[t * 4] = s;
    __syncthreads();

    float w[5];
#pragma unroll
    for (int k = 0; k < 5; k++) w[k] = convw[n * 5 + k];
    const float cb = convb[n];

    float out[4];
#pragma unroll
    for (int ff = 0; ff < 4; ff++) {
        int f = t * 4 + ff;
        float A = cb;
#pragma unroll
        for (int k = 0; k < 5; k++) {
            int idx = f + k - 2;
            if (idx >= 0 && idx < INNER_) A += ms[idx] * w[k];
        }
        float sg = 1.f / (1.f + __expf(-A));
        out[ff] = ms[f] * sg;
    }
    *(float4*)&MSg[(size_t)blk * INNER_ + t * 4] = make_float4(out[0], out[1], out[2], out[3]);

    // planar K-image write: head h = t>>4, dims d0..d0+3, token row n
    const int h  = t >> 4;
    const int d0 = (4 * t) & 63;
    unsigned short hs[4], ls[4];
#pragma unroll
    for (int e = 0; e < 4; e++) {
        unsigned int hb = f2b(out[e]);
        float fh = __uint_as_float(hb << 16);
        hs[e] = (unsigned short)hb;
        ls[e] = f2b(out[e] - fh);
    }
    unsigned short* kim = Kimg + ((size_t)(b * 8 + h) * 1024 + n) * 128 + d0;
    uint2 hv; hv.x = (unsigned int)hs[0] | ((unsigned int)hs[1] << 16);
              hv.y = (unsigned int)hs[2] | ((unsigned int)hs[3] << 16);
    uint2 lv; lv.x = (unsigned int)ls[0] | ((unsigned int)ls[1] << 16);
              lv.y = (unsigned int)ls[2] | ((unsigned int)ls[3] << 16);
    *(uint2*)kim        = hv;
    *(uint2*)(kim + 64) = lv;
}

// ---------------------------------------------------------------------------
// MFMA flash attention: 512 threads, Q-tile 128, simple 2-barrier loop.
// K staged via gll from planar image (swizzle in per-lane source offset).
// VIMG: V staged via ONE linear gll16 per thread from pre-swizzled V-image.
// IMGO: outputs as u V-images via direct register-scatter 8B stores.
// IMGA: outputs as GEMM A-image via direct register-scatter 2B stores
//       (feeds the gll out-proj GEMM; scatter stores measured free, R8).
// Softmax in log2 domain (Q pre-scaled by 0.125*log2e) with defer-max.
// ---------------------------------------------------------------------------
template<int NV, bool RESID, bool IMGO, bool IMGA, bool VIMG, int NPROB>
__global__ __launch_bounds__(512, 2)
void mattn_kernel(const float* __restrict__ Q0, const float* __restrict__ Q1,
                  const unsigned short* __restrict__ K0, const unsigned short* __restrict__ K1,
                  const float* __restrict__ VA0, const float* __restrict__ VA1,
                  const float* __restrict__ VB0, const float* __restrict__ VB1,
                  float* __restrict__ OA0, float* __restrict__ OA1,
                  float* __restrict__ OB0, float* __restrict__ OB1,
                  long long q_sb, long long q_sh, int q_sr,
                  long long k_sb, long long k_sh, int k_rs, int k_po,
                  long long v_sb, long long v_sh, int v_sr,
                  long long o_sb, long long o_sh, int o_sr)
{
    __shared__ __align__(16) unsigned short sK[64 * 128];   // hi|lo planes
    __shared__ __align__(16) unsigned short sV0[64 * 64];   // V^T plain bf16
    __shared__ __align__(16) unsigned short sV1[(NV == 2) ? 64 * 64 : 8];
    __shared__ __align__(16) unsigned short sP[128 * 64];   // P plain bf16

    const int t    = threadIdx.x;
    const int w    = t >> 6;        // wave 0..7
    const int lane = t & 63;
    const int n16  = lane & 15;
    const int quad = lane >> 4;

    // XCD-aware decode
    const int bid = blockIdx.x;
    const int c   = bid & 7;
    const int r1  = bid >> 3;
    const int qt  = r1 & 7;
    const int r2  = r1 >> 3;
    const int g   = r2 & 7;
    const int p   = (NPROB == 2) ? (r2 >> 3) : 0;
    const int bh  = 8 * g + c;
    const int b = bh >> 3, h = bh & 7;
    const int i0 = qt * 128;

    const float* Qb          = (NPROB == 2 && p) ? Q1 : Q0;
    const unsigned short* Kb = (NPROB == 2 && p) ? K1 : K0;
    const float* VAb         = (NPROB == 2 && p) ? VA1 : VA0;
    float* OAb               = (NPROB == 2 && p) ? OA1 : OA0;

    const float* Qg          = Qb + (size_t)b * q_sb + (size_t)h * q_sh;
    const unsigned short* Kg = Kb + (size_t)b * k_sb + (size_t)h * k_sh;

    const float* V0g = nullptr;
    const float* V1g = nullptr;
    const unsigned short* Vus = nullptr;
    if constexpr (VIMG) {
        Vus = (const unsigned short*)VAb + (size_t)b * v_sb + (size_t)h * v_sh;
    } else {
        V0g = VAb + (size_t)b * v_sb + (size_t)h * v_sh;
        if constexpr (NV == 2)
            V1g = VB0 + (size_t)b * v_sb + (size_t)h * v_sh;
    }

    float* O0g = nullptr; float* O1g = nullptr;
    unsigned short* img0 = nullptr; unsigned short* img1 = nullptr;
    if constexpr (IMGO) {
        img0 = (unsigned short*)OAb + (size_t)b * o_sb + (size_t)h * o_sh;
        if constexpr (NV == 2)
            img1 = (unsigned short*)OB0 + (size_t)b * o_sb + (size_t)h * o_sh;
    } else if constexpr (IMGA) {
        img0 = (unsigned short*)OAb;   // full M x 512 A-image base
    } else {
        O0g = OAb + (size_t)b * o_sb + (size_t)h * o_sh;
        if constexpr (NV == 2)
            O1g = OB0 + (size_t)b * o_sb + (size_t)h * o_sh;
    }

    // persistent Q fragments (hi/lo split), rows i0+16w+n16,
    // pre-scaled by 0.125 * log2(e) so exps are bare v_exp_f32.
    const float SC2 = 0.1803368801f;
    short8 Qh[2], Ql[2];
#pragma unroll
    for (int s = 0; s < 2; s++) {
        const float* qp = Qg + (size_t)(i0 + 16 * w + n16) * q_sr + 32 * s + 8 * quad;
        float qv[8];
        float4 q0 = *(const float4*)qp;
        float4 q1 = *(const float4*)(qp + 4);
        qv[0]=q0.x*SC2; qv[1]=q0.y*SC2; qv[2]=q0.z*SC2; qv[3]=q0.w*SC2;
        qv[4]=q1.x*SC2; qv[5]=q1.y*SC2; qv[6]=q1.z*SC2; qv[7]=q1.w*SC2;
        split8(qv, Qh[s], Ql[s]);
    }

    float m_ = -1e30f, l_ = 0.f;
    f32x4 O0a[4], O1a[(NV == 2) ? 4 : 1];
#pragma unroll
    for (int nt = 0; nt < 4; nt++) O0a[nt] = (f32x4){0.f,0.f,0.f,0.f};
    if constexpr (NV == 2) {
#pragma unroll
        for (int nt = 0; nt < 4; nt++) O1a[nt] = (f32x4){0.f,0.f,0.f,0.f};
    }

    const int prow = 16 * w + n16;          // 0..127
    const int vc = t & 15, vp = t >> 4;     // V f32 staging: d-chunk, j-pair

    // K staging: lane l of wave w fills sK rows jr=4w+(l>>4) (+32), chunk q=l&15.
    // Planar source: logical chunk lq = q ^ (jr&15) -> plane lq>>3, dchunk lq&7.
    const int jr_l = (w << 2) + (lane >> 4);
    const int lq   = (lane & 15) ^ (jr_l & 15);
    const unsigned short* kg_base = Kg + (size_t)jr_l * k_rs
                                  + (lq >> 3) * k_po + (lq & 7) * 8;
    unsigned short* sKw = &sK[w * 512];

    for (int j0 = 0; j0 < N_; j0 += 64) {
        __syncthreads();

        // ---- stage K: 2x gll16 from planar image
        {
            const unsigned short* kg = kg_base + (size_t)j0 * k_rs;
            gll16(kg, sKw);
            gll16(kg + (size_t)32 * k_rs, sKw + 4096);
        }
        // ---- stage V
        if constexpr (VIMG) {
            gll16(Vus + (size_t)(j0 >> 6) * 4096 + t * 8, &sV0[w * 512]);
        } else {
            const int j = 2 * vp;
            const float* a0 = V0g + (size_t)(j0 + j) * v_sr + 4 * vc;
            float4 va = *(const float4*)a0;
            float4 vb = *(const float4*)(a0 + v_sr);
#pragma unroll
            for (int e = 0; e < 4; e++) {
                float fa = (e==0)?va.x:(e==1)?va.y:(e==2)?va.z:va.w;
                float fb = (e==0)?vb.x:(e==1)?vb.y:(e==2)?vb.z:vb.w;
                unsigned int u = (unsigned int)f2b(fa) | ((unsigned int)f2b(fb) << 16);
                const int d = 4 * vc + e;
                const int phys = (vp >> 2) ^ ((d ^ (d >> 2)) & 7);
                *(unsigned int*)&sV0[d * 64 + (phys << 3) + (j & 7)] = u;
            }
            if constexpr (NV == 2) {
                const float* a1 = V1g + (size_t)(j0 + j) * v_sr + 4 * vc;
                float4 wa = *(const float4*)a1;
                float4 wb = *(const float4*)(a1 + v_sr);
#pragma unroll
                for (int e = 0; e < 4; e++) {
                    float fa = (e==0)?wa.x:(e==1)?wa.y:(e==2)?wa.z:wa.w;
                    float fb = (e==0)?wb.x:(e==1)?wb.y:(e==2)?wb.z:wb.w;
                    unsigned int u = (unsigned int)f2b(fa) | ((unsigned int)f2b(fb) << 16);
                    const int d = 4 * vc + e;
                    const int phys = (vp >> 2) ^ ((d ^ (d >> 2)) & 7);
                    *(unsigned int*)&sV1[d * 64 + (phys << 3) + (j & 7)] = u;
                }
            }
        }
        __syncthreads();   // drains gll vmcnt + V lgkm

        // ---- S^T = K.Q^T, split 3-MFMA, frags straight from planes
        f32x4 accS[4];
#pragma unroll
        for (int mt = 0; mt < 4; mt++) accS[mt] = (f32x4){0.f,0.f,0.f,0.f};
#pragma unroll
        for (int s = 0; s < 2; s++) {
#pragma unroll
            for (int mt = 0; mt < 4; mt++) {
                const unsigned short* kb2 = &sK[(16 * mt + n16) * 128];
                short8 kh = *(const short8*)&kb2[(((4*s + quad)    ) ^ n16) << 3];
                short8 kl = *(const short8*)&kb2[(((4*s + quad) + 8) ^ n16) << 3];
                accS[mt] = MFMA_BF16(kl, Qh[s], accS[mt], 0, 0, 0);
                accS[mt] = MFMA_BF16(kh, Ql[s], accS[mt], 0, 0, 0);
                accS[mt] = MFMA_BF16(kh, Qh[s], accS[mt], 0, 0, 0);
            }
        }

        // ---- online softmax (log2 domain), defer-max, wave-local P store
        float tmax = -1e30f;
#pragma unroll
        for (int mt = 0; mt < 4; mt++)
#pragma unroll
            for (int r = 0; r < 4; r++) tmax = fmaxf(tmax, accS[mt][r]);
        tmax = fmaxf(tmax, __shfl_xor(tmax, 16));
        tmax = fmaxf(tmax, __shfl_xor(tmax, 32));
        if (!__all(tmax <= m_ + 11.0f)) {
            const float mnew = fmaxf(m_, tmax);
            const float alpha = __builtin_amdgcn_exp2f(m_ - mnew);
            m_ = mnew;
            l_ *= alpha;
            float ar[4];
#pragma unroll
            for (int r = 0; r < 4; r++) ar[r] = __shfl(alpha, (quad << 2) + r);
#pragma unroll
            for (int nt = 0; nt < 4; nt++) {
#pragma unroll
                for (int r = 0; r < 4; r++) O0a[nt][r] *= ar[r];
                if constexpr (NV == 2)
#pragma unroll
                    for (int r = 0; r < 4; r++) O1a[nt][r] *= ar[r];
            }
        }
        float rsum = 0.f;
#pragma unroll
        for (int mt = 0; mt < 4; mt++) {
            float p0 = __builtin_amdgcn_exp2f(accS[mt][0] - m_);
            float p1 = __builtin_amdgcn_exp2f(accS[mt][1] - m_);
            float p2 = __builtin_amdgcn_exp2f(accS[mt][2] - m_);
            float p3 = __builtin_amdgcn_exp2f(accS[mt][3] - m_);
            rsum += (p0 + p1) + (p2 + p3);
            uint2 u;
            u.x = (unsigned int)f2b(p0) | ((unsigned int)f2b(p1) << 16);
            u.y = (unsigned int)f2b(p2) | ((unsigned int)f2b(p3) << 16);
            const int phys = (2 * mt + (quad >> 1)) ^ (n16 & 7);
            *(uint2*)&sP[prow * 64 + (phys << 3) + 4 * (quad & 1)] = u;
        }
        rsum += __shfl_xor(rsum, 16);
        rsum += __shfl_xor(rsum, 32);
        l_ += rsum;

        // ---- PV: plain bf16, 1 MFMA per fragment
#pragma unroll
        for (int s = 0; s < 2; s++) {
            short8 Pf = *(const short8*)&sP[prow * 64 + (((4*s + quad) ^ (n16 & 7)) << 3)];
#pragma unroll
            for (int nt = 0; nt < 4; nt++) {
                const int d = 16 * nt + n16;
                const int phys = (4*s + quad) ^ ((d ^ (d >> 2)) & 7);
                short8 vf = *(const short8*)&sV0[d * 64 + (phys << 3)];
                O0a[nt] = MFMA_BF16(Pf, vf, O0a[nt], 0, 0, 0);
                if constexpr (NV == 2) {
                    short8 vf1 = *(const short8*)&sV1[d * 64 + (phys << 3)];
                    O1a[nt] = MFMA_BF16(Pf, vf1, O1a[nt], 0, 0, 0);
                }
            }
        }
    }

    // ---- epilogue
    float linv[4];
#pragma unroll
    for (int r = 0; r < 4; r++) linv[r] = 1.0f / __shfl(l_, (quad << 2) + r);

    if constexpr (IMGO) {
        // Direct register-scatter u V-image write (8B stores).
        const int blk = 2 * qt + (w >> 2);
        const int jg  = (2 * w + (quad >> 1)) & 7;
        const int j7b = 4 * (quad & 1);
#pragma unroll
        for (int nt = 0; nt < 4; nt++) {
            const int d = 16 * nt + n16;
            const int swd = (d ^ (d >> 2)) & 7;
            const size_t off = (size_t)blk * 4096 + d * 64 + ((jg ^ swd) << 3) + j7b;
            unsigned short o0[4], o1[4];
#pragma unroll
            for (int r = 0; r < 4; r++) {
                const int row = i0 + 16 * w + 4 * quad + r;
                float v = O0a[nt][r] * linv[r];
                if constexpr (RESID) v += V0g[(size_t)row * v_sr + d];
                o0[r] = f2b(v);
                if constexpr (NV == 2) {
                    float v1 = O1a[nt][r] * linv[r];
                    if constexpr (RESID) v1 += V1g[(size_t)row * v_sr + d];
                    o1[r] = f2b(v1);
                }
            }
            uint2 u0;
            u0.x = (unsigned int)o0[0] | ((unsigned int)o0[1] << 16);
            u0.y = (unsigned int)o0[2] | ((unsigned int)o0[3] << 16);
            *(uint2*)&img0[off] = u0;
            if constexpr (NV == 2) {
                uint2 u1v;
                u1v.x = (unsigned int)o1[0] | ((unsigned int)o1[1] << 16);
                u1v.y = (unsigned int)o1[2] | ((unsigned int)o1[3] << 16);
                *(uint2*)&img1[off] = u1v;
            }
        }
    } else if constexpr (IMGA) {
        // Direct register-scatter GEMM A-image write (2B stores, R8: free).
        // row m = b*1024 + i0 + rr (rr = 16w+4quad+r), col k = h*64+16nt+n16.
        const size_t rt = (size_t)b * 8 + qt;
#pragma unroll
        for (int r = 0; r < 4; r++) {
            const int rr  = 16 * w + 4 * quad + r;
            const int s7v = rr & 7;
#pragma unroll
            for (int nt = 0; nt < 4; nt++) {
                const int k   = h * 64 + 16 * nt + n16;
                const int kt2 = k >> 5, kk = k & 31;
                unsigned short* tile = img0 + (((rt << 4) + kt2) << 13) + rr * 64;
                float v = O0a[nt][r] * linv[r];
                unsigned int hb = f2b(v);
                float fh = __uint_as_float(hb << 16);
                tile[(((kk >> 3)     ^ s7v) << 3) + (kk & 7)] = (unsigned short)hb;
                tile[((((kk >> 3)+4) ^ s7v) << 3) + (kk & 7)] = f2b(v - fh);
            }
        }
    } else {
#pragma unroll
        for (int r = 0; r < 4; r++) {
            const int row = i0 + 16 * w + 4 * quad + r;
#pragma unroll
            for (int nt = 0; nt < 4; nt++) {
                const int col = 16 * nt + n16;
                float v = O0a[nt][r] * linv[r];
                if constexpr (RESID) v += V0g[(size_t)row * v_sr + col];
                O0g[(size_t)row * o_sr + col] = v;
                if constexpr (NV == 2) {
                    float v1 = O1a[nt][r] * linv[r];
                    if constexpr (RESID) v1 += V1g[(size_t)row * v_sr + col];
                    O1g[(size_t)row * o_sr + col] = v1;
                }
            }
        }
    }
}

// ---------------------------------------------------------------------------
extern "C" void kernel_launch(void* const* d_in, const int* in_sizes, int n_in,
                              void* d_out, int out_size, void* d_ws, size_t ws_size,
                              hipStream_t stream)
{
    const float* x1    = (const float*)d_in[0];
    const float* x2    = (const float*)d_in[1];
    const float* Wqkv1 = (const float*)d_in[2];
    const float* Wqkv2 = (const float*)d_in[3];
    const float* Wout1 = (const float*)d_in[4];
    const float* bout1 = (const float*)d_in[5];
    const float* Wout2 = (const float*)d_in[6];
    const float* bout2 = (const float*)d_in[7];
    const float* convw = (const float*)d_in[8];
    const float* convb = (const float*)d_in[9];

    const size_t QKV_ELEMS = (size_t)M_ * QKVC;
    const size_t BND_ELEMS = (size_t)M_ * INNER_;
    if (ws_size < (2 * QKV_ELEMS + 5 * BND_ELEMS) * sizeof(float)) return;

    float* ws   = (float*)d_ws;
    float* qkv1 = ws;
    float* qkv2 = qkv1 + QKV_ELEMS;
    float* MSg  = qkv2 + QKV_ELEMS;
    float* u1   = MSg + BND_ELEMS;
    float* u2   = u1 + BND_ELEMS;
    float* t1m  = u2 + BND_ELEMS;
    float* t2m  = t1m + BND_ELEMS;

    // Aliased buffers (time-disjoint):
    unsigned short* x1t   = (unsigned short*)t1m;  // tiled A image, consumed step 1
    unsigned short* x2t   = (unsigned short*)t2m;  // tiled A image, consumed step 1
    unsigned short* KimgA = (unsigned short*)t1m;  // attn-A K-image, step 2 -> 3
    unsigned short* w1t   = (unsigned short*)u2;   // tiled B images, consumed step 1
    unsigned short* w2t   = w1t + (size_t)QKVC * DIM_ * 2;
    unsigned short* u1img = (unsigned short*)u1;   // u V-image, step 3 -> 4
    unsigned short* u2img = (unsigned short*)u2;
    unsigned short* t1img = (unsigned short*)t1m;  // t A-image, step 4 -> 5
    unsigned short* t2img = (unsigned short*)t2m;
    unsigned short* wo1t  = (unsigned short*)u1;   // out-proj B images (after step 4)
    unsigned short* wo2t  = wo1t + (size_t)DIM_ * DIM_ * 2;

    dim3 blk(256);

    // 0) pack activations + qkv weights into pre-swizzled tiled planar images
    pack_a_tiled<<<dim3(M_ * DIM_ / 1024), blk, 0, stream>>>(x1, x1t);
    pack_a_tiled<<<dim3(M_ * DIM_ / 1024), blk, 0, stream>>>(x2, x2t);
    pack_w_tiled<<<dim3(QKVC / 256, DIM_ / 4), blk, 0, stream>>>(Wqkv1, w1t, QKVC);
    pack_w_tiled<<<dim3(QKVC / 256, DIM_ / 4), blk, 0, stream>>>(Wqkv2, w2t, QKVC);

    // 1) QKV projections, MERGED pair (z=2); k-slice cols [512,1024) written
    //    as planar K-image into the dead k region
    gemm_gll<false, true, 2><<<dim3(QKVC / 128, M_ / 128, 2), blk, 0, stream>>>(
        x1t, x2t, w1t, w2t, nullptr, nullptr, qkv1, qkv2, M_, QKVC);

    // 2) conv + sigmoid gate -> MSg (f32) + planar K-image for attn A
    convgate_kernel<<<dim3(M_), dim3(128), 0, stream>>>(qkv1, qkv2, convw, convb,
                                                        MSg, KimgA);

    // Stride descriptors
    const long long msg_sb = (long long)N_ * INNER_, msg_sh = HD_;
    const int       msg_sr = INNER_;
    const long long qkv_sb = (long long)N_ * QKVC, qkv_sh = HD_;
    const int       qkv_sr = QKVC;
    // K-image strides (ushort units)
    const long long kA_sb = (long long)8 * N_ * 128, kA_sh = (long long)N_ * 128;
    const long long kB_sb = (long long)N_ * QKVC * 2;
    // u V-image strides (ushort units)
    const long long ui_sb = (long long)H_ * N_ * HD_, ui_sh = (long long)N_ * HD_;

    // 3) Attention A: K = KimgA (planar), Q = MSg, V = qkv v-slices (f32),
    //    +resid; outputs u1,u2 as V-images via direct register-scatter
    mattn_kernel<2, true, true, false, false, 1><<<dim3(512), dim3(512), 0, stream>>>(
        MSg, nullptr, KimgA, nullptr,
        qkv1 + 2 * INNER_, nullptr, qkv2 + 2 * INNER_, nullptr,
        (float*)u1img, nullptr, (float*)u2img, nullptr,
        msg_sb, msg_sh, msg_sr,
        kA_sb, kA_sh, 128, 64,
        qkv_sb, qkv_sh, qkv_sr,
        ui_sb, ui_sh, HD_);

    // 4) Attention B merged pair: K = qkv k-slice planar image, V = u images
    //    (one linear gll16 per tile); outputs t1m/t2m as GEMM A-images
    mattn_kernel<1, false, false, true, true, 2><<<dim3(1024), dim3(512), 0, stream>>>(
        qkv1, qkv2,
        (const unsigned short*)qkv1 + 1024, (const unsigned short*)qkv2 + 1024,
        (const float*)u1img, (const float*)u2img, nullptr, nullptr,
        (float*)t1img, (float*)t2img, nullptr, nullptr,
        qkv_sb, qkv_sh, qkv_sr,
        kB_sb, 64, QKVC * 2, 512,
        ui_sb, ui_sh, HD_,
        0, 0, 0);

    // 4.5) pack output weights into u1 (u1's last reader was step 4)
    pack_w_tiled<<<dim3(DIM_ / 256, DIM_ / 4), blk, 0, stream>>>(Wout1, wo1t, DIM_);
    pack_w_tiled<<<dim3(DIM_ / 256, DIM_ / 4), blk, 0, stream>>>(Wout2, wo2t, DIM_);

    // 5) Output projections, MERGED pair (z=2), gll staging from A-images
    float* out1 = (float*)d_out;
    float* out2 = out1 + (size_t)M_ * DIM_;
    gemm_gll<true, false, 2><<<dim3(DIM_ / 128, M_ / 128, 2), blk, 0, stream>>>(
        t1img, t2img, wo1t, wo2t, bout1, bout2, out1, out2, M_, DIM_);
}